// Round 12
// baseline (984.927 us; speedup 1.0000x reference)
//
#include <hip/hip_runtime.h>
#include <hip/hip_bf16.h>
#include <math.h>

// Problem constants
#define BB 4
#define SP 1024
#define SF 512
#define NN 1536          // SP + SF
#define DD 256
#define HH 8
#define DH 32
#define DFF 2048
#define LL 8
#define TOK (BB*NN)      // 6144
#define NSEG 48          // 1536 / 32
#define SEGLEN 32

typedef __attribute__((ext_vector_type(8))) short bf16x8;
typedef __attribute__((ext_vector_type(4))) float f32x4;
typedef __hip_bfloat16 bf16;

__device__ __forceinline__ void gld_lds16(const void* g, void* l) {
    __builtin_amdgcn_global_load_lds(
        (const __attribute__((address_space(1))) void*)g,
        (__attribute__((address_space(3))) void*)l, 16, 0, 0);
}

__device__ __forceinline__ unsigned short f2bf_u(float f) {
    return __builtin_bit_cast(unsigned short, __float2bfloat16(f));
}

// ---------------------------------------------------------------------------
// Weight prep: Wt[N][K] bf16  <-  W[K][N] fp32
// ---------------------------------------------------------------------------
__device__ __forceinline__ void wtrans_tile(
    const float* __restrict__ s, bf16* __restrict__ d, int K, int N,
    int k0, int n0)
{
    __shared__ float tile[64][65];
    int t = threadIdx.x, c = t & 63, r4 = t >> 6;
    #pragma unroll
    for (int rr = 0; rr < 64; rr += 4)
        tile[rr+r4][c] = s[(size_t)(k0+rr+r4)*N + n0 + c];
    __syncthreads();
    #pragma unroll
    for (int rr = 0; rr < 64; rr += 4) {
        int n = rr + r4;
        d[(size_t)(n0+n)*K + k0 + c] = __float2bfloat16(tile[c][n]);
    }
}

__global__ __launch_bounds__(256) void wtrans_kernel(
    const float* __restrict__ src, bf16* __restrict__ dst, int K, int N)
{
    wtrans_tile(src + (size_t)blockIdx.z*K*N, dst + (size_t)blockIdx.z*K*N,
                K, N, blockIdx.x*64, blockIdx.y*64);
}

__global__ __launch_bounds__(256) void wtrans4_kernel(
    const float* __restrict__ Wq, const float* __restrict__ Wk,
    const float* __restrict__ Wv, const float* __restrict__ Wo,
    bf16* __restrict__ Wqt, bf16* __restrict__ Wkt,
    bf16* __restrict__ Wvt, bf16* __restrict__ Wot)
{
    int z = blockIdx.z, which = z >> 3, l = z & 7;
    const float* s = (which == 0 ? Wq : which == 1 ? Wk : which == 2 ? Wv : Wo)
                     + (size_t)l*DD*DD;
    bf16* d = (which == 0 ? Wqt : which == 1 ? Wkt : which == 2 ? Wvt : Wot)
              + (size_t)l*DD*DD;
    wtrans_tile(s, d, DD, DD, blockIdx.x*64, blockIdx.y*64);
}

// ---------------------------------------------------------------------------
// bf16 MFMA GEMM core.  BM in {32,64,128}, BN=128, BK=64, 256 threads.
// BOUT (BM<=64): bf16 output with LDS-transposed coalesced stores.
// else: bias + epi (0=none,1=relu,2=elu+1), to Cb (bf16, scattered) or Cf.
// ---------------------------------------------------------------------------
template<int BM, bool BOUT>
__device__ __forceinline__ void gemm_core(
    const bf16* __restrict__ A, const bf16* __restrict__ Wt,
    const float* __restrict__ bias, float* __restrict__ Cf,
    bf16* __restrict__ Cb, int N, int K, int epi, int kc0, int kc1)
{
    constexpr int MI = BM/32;             // M-frags per wave (>=1)
    __shared__ bf16 As[BM*64];
    __shared__ bf16 Bs[128*64];
    int tid = threadIdx.x, lane = tid & 63, wid = tid >> 6;
    int m0 = blockIdx.x*BM, n0 = blockIdx.y*128;
    int wm = (wid & 1)*(BM/2), wn = (wid >> 1)*64;

    f32x4 acc[MI][4] = {};

    int rA = wid*(BM/4) + (lane >> 3);
    int rB = wid*32 + (lane >> 3);
    int c_st = (lane & 7)*8;
    const bf16* Ag = A  + (size_t)(m0 + rA)*K + c_st;
    const bf16* Bg = Wt + (size_t)(n0 + rB)*K + c_st;
    bf16* Asw = As + (wid*(BM/4))*64;     // wave-uniform LDS slab base
    bf16* Bsw = Bs + (wid*32)*64;

    int a_off = (wm + (lane & 15))*64 + (lane >> 4)*8;
    int b_off = (wn + (lane & 15))*64 + (lane >> 4)*8;

    for (int kc = kc0; kc < kc1; kc += 64) {
        #pragma unroll
        for (int i = 0; i < MI; i++)
            gld_lds16(Ag + (size_t)(i*8)*K + kc, Asw + (i*8)*64);
        #pragma unroll
        for (int i = 0; i < 4; i++)
            gld_lds16(Bg + (size_t)(i*8)*K + kc, Bsw + (i*8)*64);
        __syncthreads();
        #pragma unroll
        for (int ks = 0; ks < 2; ks++) {
            bf16x8 af[MI], bfr[4];
            #pragma unroll
            for (int i = 0; i < MI; i++)
                af[i] = *(const bf16x8*)(As + a_off + i*16*64 + ks*32);
            #pragma unroll
            for (int j = 0; j < 4; j++)
                bfr[j] = *(const bf16x8*)(Bs + b_off + j*16*64 + ks*32);
            #pragma unroll
            for (int i = 0; i < MI; i++)
                #pragma unroll
                for (int j = 0; j < 4; j++)
                    acc[i][j] = __builtin_amdgcn_mfma_f32_16x16x32_bf16(
                        af[i], bfr[j], acc[i][j], 0, 0, 0);
        }
        __syncthreads();
    }

    if constexpr (BOUT) {
        // bf16 output, coalesced via LDS transpose (reuses Bs; BM<=64)
        bf16* Ct = Bs;   // BM x 128 bf16, bank-swizzled
        #pragma unroll
        for (int j = 0; j < 4; j++) {
            int col = wn + j*16 + (lane & 15);
            float bv = bias[n0 + col];
            #pragma unroll
            for (int i = 0; i < MI; i++) {
                #pragma unroll
                for (int r = 0; r < 4; r++) {
                    int row = wm + i*16 + (lane >> 4)*4 + r;
                    float v = acc[i][j][r] + bv;
                    if (epi == 1) v = fmaxf(v, 0.f);
                    else if (epi == 2) v = (v > 0.f) ? v + 1.f : expf(v);
                    Ct[row*128 + (col ^ (((row >> 2) & 3) << 4))] = __float2bfloat16(v);
                }
            }
        }
        __syncthreads();
        constexpr int NU = BM/16;        // vec8 stores per thread
        #pragma unroll
        for (int u = 0; u < NU; u++) {
            int e = (u*256 + tid)*8;
            int row = e >> 7, c0 = e & 127;
            bf16x8 val = *(const bf16x8*)(Ct + row*128 + (c0 ^ (((row >> 2) & 3) << 4)));
            *(bf16x8*)(Cb + (size_t)(m0 + row)*N + n0 + c0) = val;
        }
    } else {
        int col_base = n0 + wn + (lane & 15);
        int row_base = m0 + wm + (lane >> 4)*4;
        #pragma unroll
        for (int j = 0; j < 4; j++) {
            int col = col_base + j*16;
            float bv = bias[col];
            #pragma unroll
            for (int i = 0; i < MI; i++) {
                #pragma unroll
                for (int r = 0; r < 4; r++) {
                    int row = row_base + i*16 + r;
                    float v = acc[i][j][r] + bv;
                    if (epi == 1) v = fmaxf(v, 0.f);
                    else if (epi == 2) v = (v > 0.f) ? v + 1.f : expf(v);
                    if (Cb) Cb[(size_t)row*N + col] = __float2bfloat16(v);
                    else    Cf[(size_t)row*N + col] = v;
                }
            }
        }
    }
}

template<int BM, bool BOUT>
__global__ __launch_bounds__(256) void mfma_gemm_kernel(
    const bf16* __restrict__ A, const bf16* __restrict__ Wt,
    const float* __restrict__ bias, float* __restrict__ Cf,
    bf16* __restrict__ Cb, int N, int K, int epi)
{
    gemm_core<BM, BOUT>(A, Wt, bias, Cf, Cb, N, K, epi, 0, K);
}

// QKV: fp32 outputs, BM=32; elu+1 for q,k
template<int BM>
__global__ __launch_bounds__(256) void mfma_qkv_kernel(
    const bf16* __restrict__ Xb,
    const bf16* __restrict__ Wqt, const bf16* __restrict__ Wkt, const bf16* __restrict__ Wvt,
    const float* __restrict__ bq, const float* __restrict__ bk, const float* __restrict__ bv,
    float* __restrict__ Q, float* __restrict__ K, float* __restrict__ V, int layer)
{
    int z = blockIdx.z;
    const bf16* Wt = (z == 0) ? Wqt : (z == 1) ? Wkt : Wvt;
    const float* b = (z == 0) ? bq : (z == 1) ? bk : bv;
    float* C = (z == 0) ? Q : (z == 1) ? K : V;
    gemm_core<BM, false>(Xb, Wt + (size_t)layer*DD*DD, b + (size_t)layer*DD,
                         C, nullptr, DD, DD, (z == 2) ? 0 : 2, 0, DD);
}

// ---------------------------------------------------------------------------
// W2 K-slice GEMM, BN=256 (full width, no A re-read): slice z of K=DFF/4,
// fp32 partials to G4 + z*TOK*DD.  grid (TOK/32, 4).
// ---------------------------------------------------------------------------
__global__ __launch_bounds__(256) void w2_slice_kernel(
    const bf16* __restrict__ A, const bf16* __restrict__ Wt,
    float* __restrict__ G4)
{
    __shared__ bf16 As[32*64];
    __shared__ bf16 Bs[256*64];
    int tid = threadIdx.x, lane = tid & 63, wid = tid >> 6;
    int m0 = blockIdx.x*32;
    int z = blockIdx.y;
    int kc0 = z*(DFF/4), kc1 = kc0 + DFF/4;
    int wn = wid*64;

    f32x4 acc[2][4] = {};

    int rA = wid*8 + (lane >> 3);
    int c_st = (lane & 7)*8;
    const bf16* Ag = A + (size_t)(m0 + rA)*DFF + c_st;
    const bf16* Bg = Wt + (size_t)(wn + (lane >> 3))*DFF + c_st;
    bf16* Asw = As + (wid*8)*64;
    bf16* Bsw = Bs + wn*64;

    int a_off = (lane & 15)*64 + (lane >> 4)*8;
    int b_off = (wn + (lane & 15))*64 + (lane >> 4)*8;

    for (int kc = kc0; kc < kc1; kc += 64) {
        gld_lds16(Ag + kc, Asw);
        #pragma unroll
        for (int i = 0; i < 8; i++)
            gld_lds16(Bg + (size_t)(i*8)*DFF + kc, Bsw + (i*8)*64);
        __syncthreads();
        #pragma unroll
        for (int ks = 0; ks < 2; ks++) {
            bf16x8 af[2], bfr[4];
            af[0] = *(const bf16x8*)(As + a_off + ks*32);
            af[1] = *(const bf16x8*)(As + a_off + 16*64 + ks*32);
            #pragma unroll
            for (int j = 0; j < 4; j++)
                bfr[j] = *(const bf16x8*)(Bs + b_off + j*16*64 + ks*32);
            #pragma unroll
            for (int i = 0; i < 2; i++)
                #pragma unroll
                for (int j = 0; j < 4; j++)
                    acc[i][j] = __builtin_amdgcn_mfma_f32_16x16x32_bf16(
                        af[i], bfr[j], acc[i][j], 0, 0, 0);
        }
        __syncthreads();
    }

    float* Gz = G4 + (size_t)z*TOK*DD;
    #pragma unroll
    for (int j = 0; j < 4; j++) {
        int c = wn + j*16 + (lane & 15);
        #pragma unroll
        for (int i = 0; i < 2; i++) {
            int row = m0 + i*16 + (lane >> 4)*4;
            #pragma unroll
            for (int r = 0; r < 4; r++)
                Gz[(size_t)(row + r)*DD + c] = acc[i][j][r];
        }
    }
}

// ---------------------------------------------------------------------------
// Fused Wo GEMM + residual + LayerNorm1:  X = LN(X + Ab@Wo + bo)
// ---------------------------------------------------------------------------
__global__ __launch_bounds__(256) void wo_ln_kernel(
    const bf16* __restrict__ A, const bf16* __restrict__ Wt,
    const float* __restrict__ bias,
    const float* __restrict__ lnw, const float* __restrict__ lnb,
    float* __restrict__ X, bf16* __restrict__ Xb)
{
    __shared__ bf16 As[32*64];
    __shared__ bf16 Bs[256*64];
    __shared__ float red[2][4][32];
    int tid = threadIdx.x, lane = tid & 63, wid = tid >> 6;
    int m0 = blockIdx.x*32;
    int wn = wid*64;

    f32x4 acc[2][4] = {};

    int rA = wid*8 + (lane >> 3);
    int c_st = (lane & 7)*8;
    const bf16* Ag = A + (size_t)(m0 + rA)*DD + c_st;
    const bf16* Bg = Wt + (size_t)(wn + (lane >> 3))*DD + c_st;
    bf16* Asw = As + (wid*8)*64;
    bf16* Bsw = Bs + wn*64;

    int a_off = (lane & 15)*64 + (lane >> 4)*8;
    int b_off = (wn + (lane & 15))*64 + (lane >> 4)*8;

    for (int kc = 0; kc < DD; kc += 64) {
        gld_lds16(Ag + kc, Asw);
        #pragma unroll
        for (int i = 0; i < 8; i++)
            gld_lds16(Bg + (size_t)(i*8)*DD + kc, Bsw + (i*8)*64);
        __syncthreads();
        #pragma unroll
        for (int ks = 0; ks < 2; ks++) {
            bf16x8 af[2], bfr[4];
            af[0] = *(const bf16x8*)(As + a_off + ks*32);
            af[1] = *(const bf16x8*)(As + a_off + 16*64 + ks*32);
            #pragma unroll
            for (int j = 0; j < 4; j++)
                bfr[j] = *(const bf16x8*)(Bs + b_off + j*16*64 + ks*32);
            #pragma unroll
            for (int i = 0; i < 2; i++)
                #pragma unroll
                for (int j = 0; j < 4; j++)
                    acc[i][j] = __builtin_amdgcn_mfma_f32_16x16x32_bf16(
                        af[i], bfr[j], acc[i][j], 0, 0, 0);
        }
        __syncthreads();
    }

    // bias + residual
    #pragma unroll
    for (int j = 0; j < 4; j++) {
        int c = wn + j*16 + (lane & 15);
        float bv = bias[c];
        #pragma unroll
        for (int i = 0; i < 2; i++) {
            int row = m0 + i*16 + (lane >> 4)*4;
            #pragma unroll
            for (int r = 0; r < 4; r++)
                acc[i][j][r] += bv + X[(size_t)(row + r)*DD + c];
        }
    }
    // per-row sums
    #pragma unroll
    for (int i = 0; i < 2; i++) {
        #pragma unroll
        for (int r = 0; r < 4; r++) {
            float s  = (acc[i][0][r] + acc[i][1][r]) + (acc[i][2][r] + acc[i][3][r]);
            float s2 = (acc[i][0][r]*acc[i][0][r] + acc[i][1][r]*acc[i][1][r])
                     + (acc[i][2][r]*acc[i][2][r] + acc[i][3][r]*acc[i][3][r]);
            #pragma unroll
            for (int off = 1; off < 16; off <<= 1) {
                s  += __shfl_xor(s,  off, 64);
                s2 += __shfl_xor(s2, off, 64);
            }
            if ((lane & 15) == 0) {
                int rloc = i*16 + (lane >> 4)*4 + r;
                red[0][wid][rloc] = s;
                red[1][wid][rloc] = s2;
            }
        }
    }
    __syncthreads();
    #pragma unroll
    for (int i = 0; i < 2; i++) {
        #pragma unroll
        for (int r = 0; r < 4; r++) {
            int rloc = i*16 + (lane >> 4)*4 + r;
            float S  = (red[0][0][rloc] + red[0][1][rloc]) + (red[0][2][rloc] + red[0][3][rloc]);
            float S2 = (red[1][0][rloc] + red[1][1][rloc]) + (red[1][2][rloc] + red[1][3][rloc]);
            float mean = S * (1.f/256.f);
            float var  = S2 * (1.f/256.f) - mean*mean;
            float rs = rsqrtf(var + 1e-5f);
            #pragma unroll
            for (int j = 0; j < 4; j++) {
                int c = wn + j*16 + (lane & 15);
                float o = (acc[i][j][r] - mean) * rs * lnw[c] + lnb[c];
                size_t idx = (size_t)(m0 + rloc)*DD + c;
                X[idx] = o;
                Xb[idx] = __float2bfloat16(o);
            }
        }
    }
}

// ---------------------------------------------------------------------------
// Encoder
// ---------------------------------------------------------------------------
__global__ __launch_bounds__(256) void encode_kernel(
    const float* __restrict__ px, const float* __restrict__ py,
    const float* __restrict__ fx, const float* __restrict__ encW,
    const float* __restrict__ encb, float* __restrict__ X, bf16* __restrict__ Xb)
{
    int tok = blockIdx.x;
    int t = threadIdx.x;
    int b = tok / NN, n = tok % NN;
    __shared__ float in[24];
    if (t < 16) {
        in[t] = (n < SP) ? px[((size_t)b*SP + n)*16 + t]
                         : fx[((size_t)b*SF + (n - SP))*16 + t];
    } else if (t < 24) {
        int j = t - 16;
        in[t] = (n < SP) ? py[((size_t)b*SP + n)*8 + j]
                         : py[((size_t)b*SP + (SP-1))*8 + j];
    }
    __syncthreads();
    float acc = encb[t];
    #pragma unroll
    for (int j = 0; j < 24; j++) acc = fmaf(in[j], encW[j*DD + t], acc);
    X[(size_t)tok*DD + t] = acc;
    Xb[(size_t)tok*DD + t] = __float2bfloat16(acc);
}

// ---------------------------------------------------------------------------
// Attention pass A (fp32 K/V): per (b,h,seg) segment sums
// ---------------------------------------------------------------------------
__global__ __launch_bounds__(256) void attnA_kernel(
    const float* __restrict__ K, const float* __restrict__ V,
    float* __restrict__ SegS, float* __restrict__ SegZ)
{
    int bid = blockIdx.x;
    int seg = bid % NSEG; int bh = bid / NSEG;
    int h = bh & 7, b = bh >> 3;
    int t = threadIdx.x;
    int d = t & 31, mg = t >> 5, m0 = mg*4;
    int tok0 = b*NN + seg*SEGLEN;
    const float* Kp = K + (size_t)tok0*DD + h*DH;
    const float* Vp = V + (size_t)tok0*DD + h*DH;
    float a0=0,a1=0,a2=0,a3=0, ks=0;
    #pragma unroll 4
    for (int i = 0; i < SEGLEN; i++) {
        float kd = Kp[(size_t)i*DD + d];
        float4 vv = *(const float4*)(Vp + (size_t)i*DD + m0);
        a0 = fmaf(kd, vv.x, a0); a1 = fmaf(kd, vv.y, a1);
        a2 = fmaf(kd, vv.z, a2); a3 = fmaf(kd, vv.w, a3);
        ks += kd;
    }
    float4 o = {a0, a1, a2, a3};
    *(float4*)(SegS + ((size_t)bid*32 + d)*32 + m0) = o;
    if (mg == 0) SegZ[(size_t)bid*32 + d] = ks;
}

// ---------------------------------------------------------------------------
// Attention pass A2: in-place exclusive prefix over segments, per (b,h).
// ---------------------------------------------------------------------------
__global__ __launch_bounds__(256) void attnA2_kernel(
    float* __restrict__ SegS, float* __restrict__ SegZ)
{
    int bh = blockIdx.x, y = blockIdx.y, t = threadIdx.x;
    int e = y*256 + t;
    float* p = SegS + (size_t)bh*NSEG*1024 + e;
    float v[NSEG];
    #pragma unroll
    for (int s = 0; s < NSEG; s++) v[s] = p[(size_t)s*1024];
    float run = 0.f;
    #pragma unroll
    for (int s = 0; s < NSEG; s++) {
        p[(size_t)s*1024] = run;
        run += v[s];
    }
    if (y == 0 && t < 32) {
        float* pz = SegZ + (size_t)bh*NSEG*32 + t;
        float vz[NSEG];
        #pragma unroll
        for (int s = 0; s < NSEG; s++) vz[s] = pz[(size_t)s*32];
        float runz = 0.f;
        #pragma unroll
        for (int s = 0; s < NSEG; s++) {
            pz[(size_t)s*32] = runz;
            runz += vz[s];
        }
    }
}

// ---------------------------------------------------------------------------
// Attention pass B (fp32 Q/K/V): one wave per (b,h,seg), 4 waves/block.
// ---------------------------------------------------------------------------
__global__ __launch_bounds__(256) void attnB_kernel(
    const float* __restrict__ Q, const float* __restrict__ K, const float* __restrict__ V,
    const float* __restrict__ SegS, const float* __restrict__ SegZ,
    bf16* __restrict__ A)
{
    int wid = threadIdx.x >> 6;
    int lane = threadIdx.x & 63;
    int bid = blockIdx.x*4 + wid;          // 0..1535
    int seg = bid % NSEG; int bh = bid / NSEG;
    int h = bh & 7, b = bh >> 3;
    int m = lane & 31, dh = lane >> 5, dh16 = dh*16;
    int tok0 = b*NN + seg*SEGLEN;

    __shared__ float qs[4][SEGLEN][32], ksm[4][SEGLEN][32], vs[4][SEGLEN][32];
    const float* Qp = Q + (size_t)tok0*DD + h*DH;
    const float* Kp = K + (size_t)tok0*DD + h*DH;
    const float* Vp = V + (size_t)tok0*DD + h*DH;
    #pragma unroll
    for (int f = lane; f < SEGLEN*8; f += 64) {
        int r = f >> 3, c = (f & 7)*4;
        *(float4*)&qs[wid][r][c]  = *(const float4*)(Qp + (size_t)r*DD + c);
        *(float4*)&ksm[wid][r][c] = *(const float4*)(Kp + (size_t)r*DD + c);
        *(float4*)&vs[wid][r][c]  = *(const float4*)(Vp + (size_t)r*DD + c);
    }
    __syncthreads();

    float kv[16], kss[16];
    const float* Pp = SegS + (size_t)bid*1024;
    const float* Zp = SegZ + (size_t)bid*32;
    #pragma unroll
    for (int j = 0; j < 16; j++) {
        kv[j]  = Pp[(dh16 + j)*32 + m];
        kss[j] = Zp[dh16 + j];
    }

    bf16* Ap = A + (size_t)tok0*DD + h*DH;
    for (int i = 0; i < SEGLEN; i++) {
        float qv[16], kk[16];
        #pragma unroll
        for (int c = 0; c < 4; c++) {
            float4 t4 = *(const float4*)&qs[wid][i][dh16 + 4*c];
            qv[4*c] = t4.x; qv[4*c+1] = t4.y; qv[4*c+2] = t4.z; qv[4*c+3] = t4.w;
            float4 k4 = *(const float4*)&ksm[wid][i][dh16 + 4*c];
            kk[4*c] = k4.x; kk[4*c+1] = k4.y; kk[4*c+2] = k4.z; kk[4*c+3] = k4.w;
        }
        float vm = vs[wid][i][m];
        #pragma unroll
        for (int j = 0; j < 16; j++) {
            kv[j] = fmaf(kk[j], vm, kv[j]);
            kss[j] += kk[j];
        }
        float p0=0,p1=0,p2=0,p3=0,z0=0,z1=0,z2=0,z3=0;
        #pragma unroll
        for (int j = 0; j < 4; j++) {
            p0 = fmaf(qv[j],     kv[j],     p0);
            p1 = fmaf(qv[4+j],   kv[4+j],   p1);
            p2 = fmaf(qv[8+j],   kv[8+j],   p2);
            p3 = fmaf(qv[12+j],  kv[12+j],  p3);
            z0 = fmaf(qv[j],     kss[j],    z0);
            z1 = fmaf(qv[4+j],   kss[4+j],  z1);
            z2 = fmaf(qv[8+j],   kss[8+j],  z2);
            z3 = fmaf(qv[12+j],  kss[12+j], z3);
        }
        float nump = (p0+p1)+(p2+p3);
        float zp   = (z0+z1)+(z2+z3);
        nump += __shfl_xor(nump, 32, 64);
        zp   += __shfl_xor(zp,   32, 64);
        if (dh == 0) Ap[(size_t)i*DD + m] = __float2bfloat16(nump / (zp + 1e-6f));
    }
}

// ---------------------------------------------------------------------------
// Residual + 4-slice sum + LayerNorm -> X fp32 and Xb bf16.
// ---------------------------------------------------------------------------
__global__ __launch_bounds__(256) void resid_ln4_kernel(
    const float* __restrict__ Xin, const float* __restrict__ G4,
    const float* __restrict__ gb,
    const float* __restrict__ w, const float* __restrict__ b,
    float* __restrict__ Xout, bf16* __restrict__ Xbout)
{
    const size_t SZ = (size_t)TOK*DD;
    int tok = blockIdx.x, t = threadIdx.x;
    size_t idx = (size_t)tok*DD + t;
    float v = Xin[idx] + gb[t]
            + ((G4[idx] + G4[SZ + idx]) + (G4[2*SZ + idx] + G4[3*SZ + idx]));
    float s = v, s2 = v*v;
    #pragma unroll
    for (int off = 32; off >= 1; off >>= 1) {
        s  += __shfl_xor(s,  off, 64);
        s2 += __shfl_xor(s2, off, 64);
    }
    __shared__ float ps[4], ps2[4];
    int wid = t >> 6;
    if ((t & 63) == 0) { ps[wid] = s; ps2[wid] = s2; }
    __syncthreads();
    float S  = ps[0] + ps[1] + ps[2] + ps[3];
    float S2 = ps2[0] + ps2[1] + ps2[2] + ps2[3];
    float mean = S * (1.f/256.f);
    float var  = S2 * (1.f/256.f) - mean*mean;
    float o = (v - mean) * rsqrtf(var + 1e-5f) * w[t] + b[t];
    Xout[idx] = o;
    Xbout[idx] = __float2bfloat16(o);
}

// ---------------------------------------------------------------------------
// Head
// ---------------------------------------------------------------------------
__global__ __launch_bounds__(256) void head_kernel(
    const float* __restrict__ X,
    const float* __restrict__ meanW, const float* __restrict__ meanB,
    const float* __restrict__ stdW,  const float* __restrict__ stdB,
    float* __restrict__ out)
{
    int wv = threadIdx.x >> 6;
    int lane = threadIdx.x & 63;
    int idx = blockIdx.x*4 + wv;
    int b = idx / SF, i = idx % SF;
    const float* row = X + ((size_t)(b*NN + SP + i))*DD;
    __shared__ float xs[4][DD];
    *(float4*)&xs[wv][lane*4] = *(const float4*)(row + lane*4);
    __syncthreads();

    int j = lane & 7;
    int which = (lane >> 3) & 1;
    int seg = lane >> 4;
    const float* W = which ? stdW : meanW;
    float p = 0.f;
    #pragma unroll 16
    for (int d = seg*64; d < seg*64 + 64; d++) p = fmaf(xs[wv][d], W[d*8 + j], p);
    p += __shfl_xor(p, 16, 64);
    p += __shfl_xor(p, 32, 64);
    if (lane < 16) {
        if (which == 0) {
            out[((size_t)b*SF + i)*8 + j] = p + meanB[j];
        } else {
            float s = p + stdB[j];
            float sp = fmaxf(s, 0.f) + log1pf(expf(-fabsf(s)));
            out[(size_t)BB*SF*8 + ((size_t)b*SF + i)*8 + j] = 0.01f + 0.99f*sp;
        }
    }
}

// ---------------------------------------------------------------------------
extern "C" void kernel_launch(void* const* d_in, const int* in_sizes, int n_in,
                              void* d_out, int out_size, void* d_ws, size_t ws_size,
                              hipStream_t stream)
{
    (void)in_sizes; (void)n_in; (void)out_size; (void)ws_size;
    const float* past_x   = (const float*)d_in[0];
    const float* past_y   = (const float*)d_in[1];
    const float* future_x = (const float*)d_in[2];
    const float* enc_W    = (const float*)d_in[3];
    const float* enc_b    = (const float*)d_in[4];
    const float* Wq       = (const float*)d_in[5];
    const float* bq       = (const float*)d_in[6];
    const float* Wk       = (const float*)d_in[7];
    const float* bk       = (const float*)d_in[8];
    const float* Wv       = (const float*)d_in[9];
    const float* bv       = (const float*)d_in[10];
    const float* Wo       = (const float*)d_in[11];
    const float* bo       = (const float*)d_in[12];
    const float* ln1_w    = (const float*)d_in[13];
    const float* ln1_b    = (const float*)d_in[14];
    const float* W1       = (const float*)d_in[15];
    const float* b1       = (const float*)d_in[16];
    const float* W2       = (const float*)d_in[17];
    const float* b2       = (const float*)d_in[18];
    const float* ln2_w    = (const float*)d_in[19];
    const float* ln2_b    = (const float*)d_in[20];
    const float* mean_W   = (const float*)d_in[21];
    const float* mean_b   = (const float*)d_in[22];
    const float* std_W    = (const float*)d_in[23];
    const float* std_b    = (const float*)d_in[24];
    float* out = (float*)d_out;

    char* base = (char*)d_ws;
    size_t off = 0;
    float* X  = (float*)(base + off); off += (size_t)TOK*DD*4;
    bf16* Xb  = (bf16*)(base + off);  off += (size_t)TOK*DD*2;
    bf16* Hb  = (bf16*)(base + off);  off += (size_t)TOK*DFF*2;   // aliased with Q/K/V
    float* Qb = (float*)Hb;
    float* Kb = Qb + (size_t)TOK*DD;
    float* Vb = Kb + (size_t)TOK*DD;
    bf16* Ab  = (bf16*)(base + off);  off += (size_t)TOK*DD*2;
    float* G4 = (float*)(base + off); off += (size_t)4*TOK*DD*4;
    float* SegS = (float*)(base + off); off += (size_t)BB*HH*NSEG*1024*4;
    float* SegZ = (float*)(base + off); off += (size_t)BB*HH*NSEG*32*4;
    bf16* Wqt = (bf16*)(base + off); off += (size_t)LL*DD*DD*2;
    bf16* Wkt = (bf16*)(base + off); off += (size_t)LL*DD*DD*2;
    bf16* Wvt = (bf16*)(base + off); off += (size_t)LL*DD*DD*2;
    bf16* Wot = (bf16*)(base + off); off += (size_t)LL*DD*DD*2;
    bf16* W1t = (bf16*)(base + off); off += (size_t)LL*DD*DFF*2;
    bf16* W2t = (bf16*)(base + off); off += (size_t)LL*DFF*DD*2;

    // Weight prep (bf16 + transpose to [N][K])
    wtrans4_kernel<<<dim3(4, 4, 4*LL), 256, 0, stream>>>(
        Wq, Wk, Wv, Wo, Wqt, Wkt, Wvt, Wot);
    wtrans_kernel<<<dim3(4, 32, LL), 256, 0, stream>>>(W1, W1t, DD, DFF);
    wtrans_kernel<<<dim3(32, 4, LL), 256, 0, stream>>>(W2, W2t, DFF, DD);

    encode_kernel<<<TOK, 256, 0, stream>>>(past_x, past_y, future_x, enc_W, enc_b, X, Xb);

    for (int l = 0; l < LL; l++) {
        mfma_qkv_kernel<32><<<dim3(TOK/32, 2, 3), 256, 0, stream>>>(
            Xb, Wqt, Wkt, Wvt, bq, bk, bv, Qb, Kb, Vb, l);
        attnA_kernel<<<BB*HH*NSEG, 256, 0, stream>>>(Kb, Vb, SegS, SegZ);
        attnA2_kernel<<<dim3(BB*HH, 4), 256, 0, stream>>>(SegS, SegZ);
        attnB_kernel<<<BB*HH*NSEG/4, 256, 0, stream>>>(Qb, Kb, Vb, SegS, SegZ, Ab);
        wo_ln_kernel<<<TOK/32, 256, 0, stream>>>(
            Ab, Wot + (size_t)l*DD*DD, bo + (size_t)l*DD,
            ln1_w + l*DD, ln1_b + l*DD, X, Xb);
        mfma_gemm_kernel<32, true><<<dim3(TOK/32, DFF/128), 256, 0, stream>>>(
            Xb, W1t + (size_t)l*DD*DFF, b1 + (size_t)l*DFF, nullptr, Hb, DFF, DD, 1);
        w2_slice_kernel<<<dim3(TOK/32, 4), 256, 0, stream>>>(
            Hb, W2t + (size_t)l*DFF*DD, G4);
        resid_ln4_kernel<<<TOK, 256, 0, stream>>>(
            X, G4, b2 + (size_t)l*DD, ln2_w + l*DD, ln2_b + l*DD, X, Xb);
    }

    head_kernel<<<(BB*SF)/4, 256, 0, stream>>>(X, mean_W, mean_b, std_W, std_b, out);
}

// Round 13
// 975.283 us; speedup vs baseline: 1.0099x; 1.0099x over previous
//
#include <hip/hip_runtime.h>
#include <hip/hip_bf16.h>
#include <math.h>

// Problem constants
#define BB 4
#define SP 1024
#define SF 512
#define NN 1536          // SP + SF
#define DD 256
#define HH 8
#define DH 32
#define DFF 2048
#define LL 8
#define TOK (BB*NN)      // 6144
#define NSEG 48          // 1536 / 32
#define SEGLEN 32

typedef __attribute__((ext_vector_type(8))) short bf16x8;
typedef __attribute__((ext_vector_type(4))) float f32x4;
typedef __hip_bfloat16 bf16;

__device__ __forceinline__ void gld_lds16(const void* g, void* l) {
    __builtin_amdgcn_global_load_lds(
        (const __attribute__((address_space(1))) void*)g,
        (__attribute__((address_space(3))) void*)l, 16, 0, 0);
}

__device__ __forceinline__ unsigned short f2bf_u(float f) {
    return __builtin_bit_cast(unsigned short, __float2bfloat16(f));
}

// ---------------------------------------------------------------------------
// Weight prep: Wt[N][K] bf16  <-  W[K][N] fp32
// ---------------------------------------------------------------------------
__device__ __forceinline__ void wtrans_tile(
    const float* __restrict__ s, bf16* __restrict__ d, int K, int N,
    int k0, int n0)
{
    __shared__ float tile[64][65];
    int t = threadIdx.x, c = t & 63, r4 = t >> 6;
    #pragma unroll
    for (int rr = 0; rr < 64; rr += 4)
        tile[rr+r4][c] = s[(size_t)(k0+rr+r4)*N + n0 + c];
    __syncthreads();
    #pragma unroll
    for (int rr = 0; rr < 64; rr += 4) {
        int n = rr + r4;
        d[(size_t)(n0+n)*K + k0 + c] = __float2bfloat16(tile[c][n]);
    }
}

__global__ __launch_bounds__(256) void wtrans_kernel(
    const float* __restrict__ src, bf16* __restrict__ dst, int K, int N)
{
    wtrans_tile(src + (size_t)blockIdx.z*K*N, dst + (size_t)blockIdx.z*K*N,
                K, N, blockIdx.x*64, blockIdx.y*64);
}

__global__ __launch_bounds__(256) void wtrans4_kernel(
    const float* __restrict__ Wq, const float* __restrict__ Wk,
    const float* __restrict__ Wv, const float* __restrict__ Wo,
    bf16* __restrict__ Wqt, bf16* __restrict__ Wkt,
    bf16* __restrict__ Wvt, bf16* __restrict__ Wot)
{
    int z = blockIdx.z, which = z >> 3, l = z & 7;
    const float* s = (which == 0 ? Wq : which == 1 ? Wk : which == 2 ? Wv : Wo)
                     + (size_t)l*DD*DD;
    bf16* d = (which == 0 ? Wqt : which == 1 ? Wkt : which == 2 ? Wvt : Wot)
              + (size_t)l*DD*DD;
    wtrans_tile(s, d, DD, DD, blockIdx.x*64, blockIdx.y*64);
}

// ---------------------------------------------------------------------------
// bf16 MFMA GEMM core.  BM in {32,64,128}, BN=128, BK=64, 256 threads.
// BOUT (BM<=64): bf16 output with LDS-transposed coalesced stores.
// else: bias + epi (0=none,1=relu,2=elu+1), to Cb (bf16, scattered) or Cf.
// ---------------------------------------------------------------------------
template<int BM, bool BOUT>
__device__ __forceinline__ void gemm_core(
    const bf16* __restrict__ A, const bf16* __restrict__ Wt,
    const float* __restrict__ bias, float* __restrict__ Cf,
    bf16* __restrict__ Cb, int N, int K, int epi, int kc0, int kc1)
{
    constexpr int MI = BM/32;             // M-frags per wave (>=1)
    __shared__ bf16 As[BM*64];
    __shared__ bf16 Bs[128*64];
    int tid = threadIdx.x, lane = tid & 63, wid = tid >> 6;
    int m0 = blockIdx.x*BM, n0 = blockIdx.y*128;
    int wm = (wid & 1)*(BM/2), wn = (wid >> 1)*64;

    f32x4 acc[MI][4] = {};

    int rA = wid*(BM/4) + (lane >> 3);
    int rB = wid*32 + (lane >> 3);
    int c_st = (lane & 7)*8;
    const bf16* Ag = A  + (size_t)(m0 + rA)*K + c_st;
    const bf16* Bg = Wt + (size_t)(n0 + rB)*K + c_st;
    bf16* Asw = As + (wid*(BM/4))*64;     // wave-uniform LDS slab base
    bf16* Bsw = Bs + (wid*32)*64;

    int a_off = (wm + (lane & 15))*64 + (lane >> 4)*8;
    int b_off = (wn + (lane & 15))*64 + (lane >> 4)*8;

    for (int kc = kc0; kc < kc1; kc += 64) {
        #pragma unroll
        for (int i = 0; i < MI; i++)
            gld_lds16(Ag + (size_t)(i*8)*K + kc, Asw + (i*8)*64);
        #pragma unroll
        for (int i = 0; i < 4; i++)
            gld_lds16(Bg + (size_t)(i*8)*K + kc, Bsw + (i*8)*64);
        __syncthreads();
        #pragma unroll
        for (int ks = 0; ks < 2; ks++) {
            bf16x8 af[MI], bfr[4];
            #pragma unroll
            for (int i = 0; i < MI; i++)
                af[i] = *(const bf16x8*)(As + a_off + i*16*64 + ks*32);
            #pragma unroll
            for (int j = 0; j < 4; j++)
                bfr[j] = *(const bf16x8*)(Bs + b_off + j*16*64 + ks*32);
            #pragma unroll
            for (int i = 0; i < MI; i++)
                #pragma unroll
                for (int j = 0; j < 4; j++)
                    acc[i][j] = __builtin_amdgcn_mfma_f32_16x16x32_bf16(
                        af[i], bfr[j], acc[i][j], 0, 0, 0);
        }
        __syncthreads();
    }

    if constexpr (BOUT) {
        // bf16 output, coalesced via LDS transpose (reuses Bs; BM<=64)
        bf16* Ct = Bs;   // BM x 128 bf16, bank-swizzled
        #pragma unroll
        for (int j = 0; j < 4; j++) {
            int col = wn + j*16 + (lane & 15);
            float bv = bias[n0 + col];
            #pragma unroll
            for (int i = 0; i < MI; i++) {
                #pragma unroll
                for (int r = 0; r < 4; r++) {
                    int row = wm + i*16 + (lane >> 4)*4 + r;
                    float v = acc[i][j][r] + bv;
                    if (epi == 1) v = fmaxf(v, 0.f);
                    else if (epi == 2) v = (v > 0.f) ? v + 1.f : expf(v);
                    Ct[row*128 + (col ^ (((row >> 2) & 3) << 4))] = __float2bfloat16(v);
                }
            }
        }
        __syncthreads();
        constexpr int NU = BM/16;        // vec8 stores per thread
        #pragma unroll
        for (int u = 0; u < NU; u++) {
            int e = (u*256 + tid)*8;
            int row = e >> 7, c0 = e & 127;
            bf16x8 val = *(const bf16x8*)(Ct + row*128 + (c0 ^ (((row >> 2) & 3) << 4)));
            *(bf16x8*)(Cb + (size_t)(m0 + row)*N + n0 + c0) = val;
        }
    } else {
        int col_base = n0 + wn + (lane & 15);
        int row_base = m0 + wm + (lane >> 4)*4;
        #pragma unroll
        for (int j = 0; j < 4; j++) {
            int col = col_base + j*16;
            float bv = bias[col];
            #pragma unroll
            for (int i = 0; i < MI; i++) {
                #pragma unroll
                for (int r = 0; r < 4; r++) {
                    int row = row_base + i*16 + r;
                    float v = acc[i][j][r] + bv;
                    if (epi == 1) v = fmaxf(v, 0.f);
                    else if (epi == 2) v = (v > 0.f) ? v + 1.f : expf(v);
                    if (Cb) Cb[(size_t)row*N + col] = __float2bfloat16(v);
                    else    Cf[(size_t)row*N + col] = v;
                }
            }
        }
    }
}

template<int BM, bool BOUT>
__global__ __launch_bounds__(256) void mfma_gemm_kernel(
    const bf16* __restrict__ A, const bf16* __restrict__ Wt,
    const float* __restrict__ bias, float* __restrict__ Cf,
    bf16* __restrict__ Cb, int N, int K, int epi)
{
    gemm_core<BM, BOUT>(A, Wt, bias, Cf, Cb, N, K, epi, 0, K);
}

// QKV: fp32 outputs, BM=32; elu+1 for q,k
template<int BM>
__global__ __launch_bounds__(256) void mfma_qkv_kernel(
    const bf16* __restrict__ Xb,
    const bf16* __restrict__ Wqt, const bf16* __restrict__ Wkt, const bf16* __restrict__ Wvt,
    const float* __restrict__ bq, const float* __restrict__ bk, const float* __restrict__ bv,
    float* __restrict__ Q, float* __restrict__ K, float* __restrict__ V, int layer)
{
    int z = blockIdx.z;
    const bf16* Wt = (z == 0) ? Wqt : (z == 1) ? Wkt : Wvt;
    const float* b = (z == 0) ? bq : (z == 1) ? bk : bv;
    float* C = (z == 0) ? Q : (z == 1) ? K : V;
    gemm_core<BM, false>(Xb, Wt + (size_t)layer*DD*DD, b + (size_t)layer*DD,
                         C, nullptr, DD, DD, (z == 2) ? 0 : 2, 0, DD);
}

// ---------------------------------------------------------------------------
// W2 K-slice GEMM, BN=256 (full width): slice z of K=DFF/4, fp32 partials.
// ---------------------------------------------------------------------------
__global__ __launch_bounds__(256) void w2_slice_kernel(
    const bf16* __restrict__ A, const bf16* __restrict__ Wt,
    float* __restrict__ G4)
{
    __shared__ bf16 As[32*64];
    __shared__ bf16 Bs[256*64];
    int tid = threadIdx.x, lane = tid & 63, wid = tid >> 6;
    int m0 = blockIdx.x*32;
    int z = blockIdx.y;
    int kc0 = z*(DFF/4), kc1 = kc0 + DFF/4;
    int wn = wid*64;

    f32x4 acc[2][4] = {};

    int rA = wid*8 + (lane >> 3);
    int c_st = (lane & 7)*8;
    const bf16* Ag = A + (size_t)(m0 + rA)*DFF + c_st;
    const bf16* Bg = Wt + (size_t)(wn + (lane >> 3))*DFF + c_st;
    bf16* Asw = As + (wid*8)*64;
    bf16* Bsw = Bs + wn*64;

    int a_off = (lane & 15)*64 + (lane >> 4)*8;
    int b_off = (wn + (lane & 15))*64 + (lane >> 4)*8;

    for (int kc = kc0; kc < kc1; kc += 64) {
        gld_lds16(Ag + kc, Asw);
        #pragma unroll
        for (int i = 0; i < 8; i++)
            gld_lds16(Bg + (size_t)(i*8)*DFF + kc, Bsw + (i*8)*64);
        __syncthreads();
        #pragma unroll
        for (int ks = 0; ks < 2; ks++) {
            bf16x8 af[2], bfr[4];
            af[0] = *(const bf16x8*)(As + a_off + ks*32);
            af[1] = *(const bf16x8*)(As + a_off + 16*64 + ks*32);
            #pragma unroll
            for (int j = 0; j < 4; j++)
                bfr[j] = *(const bf16x8*)(Bs + b_off + j*16*64 + ks*32);
            #pragma unroll
            for (int i = 0; i < 2; i++)
                #pragma unroll
                for (int j = 0; j < 4; j++)
                    acc[i][j] = __builtin_amdgcn_mfma_f32_16x16x32_bf16(
                        af[i], bfr[j], acc[i][j], 0, 0, 0);
        }
        __syncthreads();
    }

    float* Gz = G4 + (size_t)z*TOK*DD;
    #pragma unroll
    for (int j = 0; j < 4; j++) {
        int c = wn + j*16 + (lane & 15);
        #pragma unroll
        for (int i = 0; i < 2; i++) {
            int row = m0 + i*16 + (lane >> 4)*4;
            #pragma unroll
            for (int r = 0; r < 4; r++)
                Gz[(size_t)(row + r)*DD + c] = acc[i][j][r];
        }
    }
}

// ---------------------------------------------------------------------------
// Fused Wo GEMM + residual + LayerNorm1:  X = LN(X + Ab@Wo + bo)
// ---------------------------------------------------------------------------
__global__ __launch_bounds__(256) void wo_ln_kernel(
    const bf16* __restrict__ A, const bf16* __restrict__ Wt,
    const float* __restrict__ bias,
    const float* __restrict__ lnw, const float* __restrict__ lnb,
    float* __restrict__ X, bf16* __restrict__ Xb)
{
    __shared__ bf16 As[32*64];
    __shared__ bf16 Bs[256*64];
    __shared__ float red[2][4][32];
    int tid = threadIdx.x, lane = tid & 63, wid = tid >> 6;
    int m0 = blockIdx.x*32;
    int wn = wid*64;

    f32x4 acc[2][4] = {};

    int rA = wid*8 + (lane >> 3);
    int c_st = (lane & 7)*8;
    const bf16* Ag = A + (size_t)(m0 + rA)*DD + c_st;
    const bf16* Bg = Wt + (size_t)(wn + (lane >> 3))*DD + c_st;
    bf16* Asw = As + (wid*8)*64;
    bf16* Bsw = Bs + wn*64;

    int a_off = (lane & 15)*64 + (lane >> 4)*8;
    int b_off = (wn + (lane & 15))*64 + (lane >> 4)*8;

    for (int kc = 0; kc < DD; kc += 64) {
        gld_lds16(Ag + kc, Asw);
        #pragma unroll
        for (int i = 0; i < 8; i++)
            gld_lds16(Bg + (size_t)(i*8)*DD + kc, Bsw + (i*8)*64);
        __syncthreads();
        #pragma unroll
        for (int ks = 0; ks < 2; ks++) {
            bf16x8 af[2], bfr[4];
            af[0] = *(const bf16x8*)(As + a_off + ks*32);
            af[1] = *(const bf16x8*)(As + a_off + 16*64 + ks*32);
            #pragma unroll
            for (int j = 0; j < 4; j++)
                bfr[j] = *(const bf16x8*)(Bs + b_off + j*16*64 + ks*32);
            #pragma unroll
            for (int i = 0; i < 2; i++)
                #pragma unroll
                for (int j = 0; j < 4; j++)
                    acc[i][j] = __builtin_amdgcn_mfma_f32_16x16x32_bf16(
                        af[i], bfr[j], acc[i][j], 0, 0, 0);
        }
        __syncthreads();
    }

    // bias + residual
    #pragma unroll
    for (int j = 0; j < 4; j++) {
        int c = wn + j*16 + (lane & 15);
        float bv = bias[c];
        #pragma unroll
        for (int i = 0; i < 2; i++) {
            int row = m0 + i*16 + (lane >> 4)*4;
            #pragma unroll
            for (int r = 0; r < 4; r++)
                acc[i][j][r] += bv + X[(size_t)(row + r)*DD + c];
        }
    }
    // per-row sums
    #pragma unroll
    for (int i = 0; i < 2; i++) {
        #pragma unroll
        for (int r = 0; r < 4; r++) {
            float s  = (acc[i][0][r] + acc[i][1][r]) + (acc[i][2][r] + acc[i][3][r]);
            float s2 = (acc[i][0][r]*acc[i][0][r] + acc[i][1][r]*acc[i][1][r])
                     + (acc[i][2][r]*acc[i][2][r] + acc[i][3][r]*acc[i][3][r]);
            #pragma unroll
            for (int off = 1; off < 16; off <<= 1) {
                s  += __shfl_xor(s,  off, 64);
                s2 += __shfl_xor(s2, off, 64);
            }
            if ((lane & 15) == 0) {
                int rloc = i*16 + (lane >> 4)*4 + r;
                red[0][wid][rloc] = s;
                red[1][wid][rloc] = s2;
            }
        }
    }
    __syncthreads();
    #pragma unroll
    for (int i = 0; i < 2; i++) {
        #pragma unroll
        for (int r = 0; r < 4; r++) {
            int rloc = i*16 + (lane >> 4)*4 + r;
            float S  = (red[0][0][rloc] + red[0][1][rloc]) + (red[0][2][rloc] + red[0][3][rloc]);
            float S2 = (red[1][0][rloc] + red[1][1][rloc]) + (red[1][2][rloc] + red[1][3][rloc]);
            float mean = S * (1.f/256.f);
            float var  = S2 * (1.f/256.f) - mean*mean;
            float rs = rsqrtf(var + 1e-5f);
            #pragma unroll
            for (int j = 0; j < 4; j++) {
                int c = wn + j*16 + (lane & 15);
                float o = (acc[i][j][r] - mean) * rs * lnw[c] + lnb[c];
                size_t idx = (size_t)(m0 + rloc)*DD + c;
                X[idx] = o;
                Xb[idx] = __float2bfloat16(o);
            }
        }
    }
}

// ---------------------------------------------------------------------------
// Encoder
// ---------------------------------------------------------------------------
__global__ __launch_bounds__(256) void encode_kernel(
    const float* __restrict__ px, const float* __restrict__ py,
    const float* __restrict__ fx, const float* __restrict__ encW,
    const float* __restrict__ encb, float* __restrict__ X, bf16* __restrict__ Xb)
{
    int tok = blockIdx.x;
    int t = threadIdx.x;
    int b = tok / NN, n = tok % NN;
    __shared__ float in[24];
    if (t < 16) {
        in[t] = (n < SP) ? px[((size_t)b*SP + n)*16 + t]
                         : fx[((size_t)b*SF + (n - SP))*16 + t];
    } else if (t < 24) {
        int j = t - 16;
        in[t] = (n < SP) ? py[((size_t)b*SP + n)*8 + j]
                         : py[((size_t)b*SP + (SP-1))*8 + j];
    }
    __syncthreads();
    float acc = encb[t];
    #pragma unroll
    for (int j = 0; j < 24; j++) acc = fmaf(in[j], encW[j*DD + t], acc);
    X[(size_t)tok*DD + t] = acc;
    Xb[(size_t)tok*DD + t] = __float2bfloat16(acc);
}

// ---------------------------------------------------------------------------
// Attention pass A (fp32 K/V): per (b,h,seg) segment sums
// ---------------------------------------------------------------------------
__global__ __launch_bounds__(256) void attnA_kernel(
    const float* __restrict__ K, const float* __restrict__ V,
    float* __restrict__ SegS, float* __restrict__ SegZ)
{
    int bid = blockIdx.x;
    int seg = bid % NSEG; int bh = bid / NSEG;
    int h = bh & 7, b = bh >> 3;
    int t = threadIdx.x;
    int d = t & 31, mg = t >> 5, m0 = mg*4;
    int tok0 = b*NN + seg*SEGLEN;
    const float* Kp = K + (size_t)tok0*DD + h*DH;
    const float* Vp = V + (size_t)tok0*DD + h*DH;
    float a0=0,a1=0,a2=0,a3=0, ks=0;
    #pragma unroll 4
    for (int i = 0; i < SEGLEN; i++) {
        float kd = Kp[(size_t)i*DD + d];
        float4 vv = *(const float4*)(Vp + (size_t)i*DD + m0);
        a0 = fmaf(kd, vv.x, a0); a1 = fmaf(kd, vv.y, a1);
        a2 = fmaf(kd, vv.z, a2); a3 = fmaf(kd, vv.w, a3);
        ks += kd;
    }
    float4 o = {a0, a1, a2, a3};
    *(float4*)(SegS + ((size_t)bid*32 + d)*32 + m0) = o;
    if (mg == 0) SegZ[(size_t)bid*32 + d] = ks;
}

// ---------------------------------------------------------------------------
// Attention pass A2: in-place exclusive prefix over segments, per (b,h).
// ---------------------------------------------------------------------------
__global__ __launch_bounds__(256) void attnA2_kernel(
    float* __restrict__ SegS, float* __restrict__ SegZ)
{
    int bh = blockIdx.x, y = blockIdx.y, t = threadIdx.x;
    int e = y*256 + t;
    float* p = SegS + (size_t)bh*NSEG*1024 + e;
    float v[NSEG];
    #pragma unroll
    for (int s = 0; s < NSEG; s++) v[s] = p[(size_t)s*1024];
    float run = 0.f;
    #pragma unroll
    for (int s = 0; s < NSEG; s++) {
        p[(size_t)s*1024] = run;
        run += v[s];
    }
    if (y == 0 && t < 32) {
        float* pz = SegZ + (size_t)bh*NSEG*32 + t;
        float vz[NSEG];
        #pragma unroll
        for (int s = 0; s < NSEG; s++) vz[s] = pz[(size_t)s*32];
        float runz = 0.f;
        #pragma unroll
        for (int s = 0; s < NSEG; s++) {
            pz[(size_t)s*32] = runz;
            runz += vz[s];
        }
    }
}

// ---------------------------------------------------------------------------
// Attention pass B: TWO waves per (b,h,seg), 4 waves/block (2 segments).
// Wave half = (tid>>6)&1 owns m = half*16 + (lane&15); d-group = lane>>4
// owns 8 d's.  Dot reduced across d-groups via shfl_xor(16,32).
// ---------------------------------------------------------------------------
__global__ __launch_bounds__(256) void attnB_kernel(
    const float* __restrict__ Q, const float* __restrict__ K, const float* __restrict__ V,
    const float* __restrict__ SegS, const float* __restrict__ SegZ,
    bf16* __restrict__ A)
{
    int tid = threadIdx.x;
    int sidx = tid >> 7;                 // segment slot in block (0..1)
    int half = (tid >> 6) & 1;           // m-half
    int lane = tid & 63;
    int bid = blockIdx.x*2 + sidx;       // 0..1535
    int seg = bid % NSEG; int bh = bid / NSEG;
    int h = bh & 7, b = bh >> 3;
    int m = half*16 + (lane & 15);       // 0..31
    int d0 = (lane >> 4)*8;              // d-group base
    int tok0 = b*NN + seg*SEGLEN;

    __shared__ float qs[2][SEGLEN][32], ksm[2][SEGLEN][32], vs[2][SEGLEN][32];
    const float* Qp = Q + (size_t)tok0*DD + h*DH;
    const float* Kp = K + (size_t)tok0*DD + h*DH;
    const float* Vp = V + (size_t)tok0*DD + h*DH;
    int lt = tid & 127;                  // 128 threads per segment
    #pragma unroll
    for (int f = lt; f < SEGLEN*8; f += 128) {
        int r = f >> 3, c = (f & 7)*4;
        *(float4*)&qs[sidx][r][c]  = *(const float4*)(Qp + (size_t)r*DD + c);
        *(float4*)&ksm[sidx][r][c] = *(const float4*)(Kp + (size_t)r*DD + c);
        *(float4*)&vs[sidx][r][c]  = *(const float4*)(Vp + (size_t)r*DD + c);
    }
    __syncthreads();

    float kv[8], kss[8];
    const float* Pp = SegS + (size_t)bid*1024;
    const float* Zp = SegZ + (size_t)bid*32;
    #pragma unroll
    for (int j = 0; j < 8; j++) {
        kv[j]  = Pp[(d0 + j)*32 + m];
        kss[j] = Zp[d0 + j];
    }

    bf16* Ap = A + (size_t)tok0*DD + h*DH;
    for (int i = 0; i < SEGLEN; i++) {
        float qv[8], kk[8];
        #pragma unroll
        for (int c = 0; c < 2; c++) {
            float4 t4 = *(const float4*)&qs[sidx][i][d0 + 4*c];
            qv[4*c] = t4.x; qv[4*c+1] = t4.y; qv[4*c+2] = t4.z; qv[4*c+3] = t4.w;
            float4 k4 = *(const float4*)&ksm[sidx][i][d0 + 4*c];
            kk[4*c] = k4.x; kk[4*c+1] = k4.y; kk[4*c+2] = k4.z; kk[4*c+3] = k4.w;
        }
        float vm = vs[sidx][i][m];
        #pragma unroll
        for (int j = 0; j < 8; j++) {
            kv[j] = fmaf(kk[j], vm, kv[j]);
            kss[j] += kk[j];
        }
        float p0=0,p1=0,z0=0,z1=0;
        #pragma unroll
        for (int j = 0; j < 4; j++) {
            p0 = fmaf(qv[j],   kv[j],   p0);
            p1 = fmaf(qv[4+j], kv[4+j], p1);
            z0 = fmaf(qv[j],   kss[j],  z0);
            z1 = fmaf(qv[4+j], kss[4+j],z1);
        }
        float nump = p0 + p1;
        float zp   = z0 + z1;
        nump += __shfl_xor(nump, 16, 64);
        nump += __shfl_xor(nump, 32, 64);
        zp   += __shfl_xor(zp,   16, 64);
        zp   += __shfl_xor(zp,   32, 64);
        if ((lane >> 4) == 0)    // lanes 0..15 hold the full sums
            Ap[(size_t)i*DD + m] = __float2bfloat16(nump / (zp + 1e-6f));
    }
}

// ---------------------------------------------------------------------------
// Residual + 4-slice sum + LayerNorm -> X fp32 and Xb bf16.
// ---------------------------------------------------------------------------
__global__ __launch_bounds__(256) void resid_ln4_kernel(
    const float* __restrict__ Xin, const float* __restrict__ G4,
    const float* __restrict__ gb,
    const float* __restrict__ w, const float* __restrict__ b,
    float* __restrict__ Xout, bf16* __restrict__ Xbout)
{
    const size_t SZ = (size_t)TOK*DD;
    int tok = blockIdx.x, t = threadIdx.x;
    size_t idx = (size_t)tok*DD + t;
    float v = Xin[idx] + gb[t]
            + ((G4[idx] + G4[SZ + idx]) + (G4[2*SZ + idx] + G4[3*SZ + idx]));
    float s = v, s2 = v*v;
    #pragma unroll
    for (int off = 32; off >= 1; off >>= 1) {
        s  += __shfl_xor(s,  off, 64);
        s2 += __shfl_xor(s2, off, 64);
    }
    __shared__ float ps[4], ps2[4];
    int wid = t >> 6;
    if ((t & 63) == 0) { ps[wid] = s; ps2[wid] = s2; }
    __syncthreads();
    float S  = ps[0] + ps[1] + ps[2] + ps[3];
    float S2 = ps2[0] + ps2[1] + ps2[2] + ps2[3];
    float mean = S * (1.f/256.f);
    float var  = S2 * (1.f/256.f) - mean*mean;
    float o = (v - mean) * rsqrtf(var + 1e-5f) * w[t] + b[t];
    Xout[idx] = o;
    Xbout[idx] = __float2bfloat16(o);
}

// ---------------------------------------------------------------------------
// Head
// ---------------------------------------------------------------------------
__global__ __launch_bounds__(256) void head_kernel(
    const float* __restrict__ X,
    const float* __restrict__ meanW, const float* __restrict__ meanB,
    const float* __restrict__ stdW,  const float* __restrict__ stdB,
    float* __restrict__ out)
{
    int wv = threadIdx.x >> 6;
    int lane = threadIdx.x & 63;
    int idx = blockIdx.x*4 + wv;
    int b = idx / SF, i = idx % SF;
    const float* row = X + ((size_t)(b*NN + SP + i))*DD;
    __shared__ float xs[4][DD];
    *(float4*)&xs[wv][lane*4] = *(const float4*)(row + lane*4);
    __syncthreads();

    int j = lane & 7;
    int which = (lane >> 3) & 1;
    int seg = lane >> 4;
    const float* W = which ? stdW : meanW;
    float p = 0.f;
    #pragma unroll 16
    for (int d = seg*64; d < seg*64 + 64; d++) p = fmaf(xs[wv][d], W[d*8 + j], p);
    p += __shfl_xor(p, 16, 64);
    p += __shfl_xor(p, 32, 64);
    if (lane < 16) {
        if (which == 0) {
            out[((size_t)b*SF + i)*8 + j] = p + meanB[j];
        } else {
            float s = p + stdB[j];
            float sp = fmaxf(s, 0.f) + log1pf(expf(-fabsf(s)));
            out[(size_t)BB*SF*8 + ((size_t)b*SF + i)*8 + j] = 0.01f + 0.99f*sp;
        }
    }
}

// ---------------------------------------------------------------------------
extern "C" void kernel_launch(void* const* d_in, const int* in_sizes, int n_in,
                              void* d_out, int out_size, void* d_ws, size_t ws_size,
                              hipStream_t stream)
{
    (void)in_sizes; (void)n_in; (void)out_size; (void)ws_size;
    const float* past_x   = (const float*)d_in[0];
    const float* past_y   = (const float*)d_in[1];
    const float* future_x = (const float*)d_in[2];
    const float* enc_W    = (const float*)d_in[3];
    const float* enc_b    = (const float*)d_in[4];
    const float* Wq       = (const float*)d_in[5];
    const float* bq       = (const float*)d_in[6];
    const float* Wk       = (const float*)d_in[7];
    const float* bk       = (const float*)d_in[8];
    const float* Wv       = (const float*)d_in[9];
    const float* bv       = (const float*)d_in[10];
    const float* Wo       = (const float*)d_in[11];
    const float* bo       = (const float*)d_in[12];
    const float* ln1_w    = (const float*)d_in[13];
    const float* ln1_b    = (const float*)d_in[14];
    const float* W1       = (const float*)d_in[15];
    const float* b1       = (const float*)d_in[16];
    const float* W2       = (const float*)d_in[17];
    const float* b2       = (const float*)d_in[18];
    const float* ln2_w    = (const float*)d_in[19];
    const float* ln2_b    = (const float*)d_in[20];
    const float* mean_W   = (const float*)d_in[21];
    const float* mean_b   = (const float*)d_in[22];
    const float* std_W    = (const float*)d_in[23];
    const float* std_b    = (const float*)d_in[24];
    float* out = (float*)d_out;

    char* base = (char*)d_ws;
    size_t off = 0;
    float* X  = (float*)(base + off); off += (size_t)TOK*DD*4;
    bf16* Xb  = (bf16*)(base + off);  off += (size_t)TOK*DD*2;
    bf16* Hb  = (bf16*)(base + off);  off += (size_t)TOK*DFF*2;   // aliased with Q/K/V
    float* Qb = (float*)Hb;
    float* Kb = Qb + (size_t)TOK*DD;
    float* Vb = Kb + (size_t)TOK*DD;
    bf16* Ab  = (bf16*)(base + off);  off += (size_t)TOK*DD*2;
    float* G4 = (float*)(base + off); off += (size_t)4*TOK*DD*4;
    float* SegS = (float*)(base + off); off += (size_t)BB*HH*NSEG*1024*4;
    float* SegZ = (float*)(base + off); off += (size_t)BB*HH*NSEG*32*4;
    bf16* Wqt = (bf16*)(base + off); off += (size_t)LL*DD*DD*2;
    bf16* Wkt = (bf16*)(base + off); off += (size_t)LL*DD*DD*2;
    bf16* Wvt = (bf16*)(base + off); off += (size_t)LL*DD*DD*2;
    bf16* Wot = (bf16*)(base + off); off += (size_t)LL*DD*DD*2;
    bf16* W1t = (bf16*)(base + off); off += (size_t)LL*DD*DFF*2;
    bf16* W2t = (bf16*)(base + off); off += (size_t)LL*DFF*DD*2;

    // Weight prep (bf16 + transpose to [N][K])
    wtrans4_kernel<<<dim3(4, 4, 4*LL), 256, 0, stream>>>(
        Wq, Wk, Wv, Wo, Wqt, Wkt, Wvt, Wot);
    wtrans_kernel<<<dim3(4, 32, LL), 256, 0, stream>>>(W1, W1t, DD, DFF);
    wtrans_kernel<<<dim3(32, 4, LL), 256, 0, stream>>>(W2, W2t, DFF, DD);

    encode_kernel<<<TOK, 256, 0, stream>>>(past_x, past_y, future_x, enc_W, enc_b, X, Xb);

    for (int l = 0; l < LL; l++) {
        mfma_qkv_kernel<32><<<dim3(TOK/32, 2, 3), 256, 0, stream>>>(
            Xb, Wqt, Wkt, Wvt, bq, bk, bv, Qb, Kb, Vb, l);
        attnA_kernel<<<BB*HH*NSEG, 256, 0, stream>>>(Kb, Vb, SegS, SegZ);
        attnA2_kernel<<<dim3(BB*HH, 4), 256, 0, stream>>>(SegS, SegZ);
        attnB_kernel<<<BB*HH*NSEG/2, 256, 0, stream>>>(Qb, Kb, Vb, SegS, SegZ, Ab);
        wo_ln_kernel<<<TOK/32, 256, 0, stream>>>(
            Ab, Wot + (size_t)l*DD*DD, bo + (size_t)l*DD,
            ln1_w + l*DD, ln1_b + l*DD, X, Xb);
        mfma_gemm_kernel<32, true><<<dim3(TOK/32, DFF/128), 256, 0, stream>>>(
            Xb, W1t + (size_t)l*DD*DFF, b1 + (size_t)l*DFF, nullptr, Hb, DFF, DD, 1);
        w2_slice_kernel<<<dim3(TOK/32, 4), 256, 0, stream>>>(
            Hb, W2t + (size_t)l*DFF*DD, G4);
        resid_ln4_kernel<<<TOK, 256, 0, stream>>>(
            X, G4, b2 + (size_t)l*DD, ln2_w + l*DD, ln2_b + l*DD, X, Xb);
    }

    head_kernel<<<(BB*SF)/4, 256, 0, stream>>>(X, mean_W, mean_b, std_W, std_b, out);
}

// Round 14
// 944.345 us; speedup vs baseline: 1.0430x; 1.0328x over previous
//
#include <hip/hip_runtime.h>
#include <hip/hip_bf16.h>
#include <math.h>

// Problem constants
#define BB 4
#define SP 1024
#define SF 512
#define NN 1536          // SP + SF
#define DD 256
#define HH 8
#define DH 32
#define DFF 2048
#define LL 8
#define TOK (BB*NN)      // 6144
#define FTOK (BB*SF)     // 2048 future tokens
#define NSEG 48          // 1536 / 32
#define SEGLEN 32

typedef __attribute__((ext_vector_type(8))) short bf16x8;
typedef __attribute__((ext_vector_type(4))) float f32x4;
typedef __hip_bfloat16 bf16;

__device__ __forceinline__ void gld_lds16(const void* g, void* l) {
    __builtin_amdgcn_global_load_lds(
        (const __attribute__((address_space(1))) void*)g,
        (__attribute__((address_space(3))) void*)l, 16, 0, 0);
}

__device__ __forceinline__ unsigned short f2bf_u(float f) {
    return __builtin_bit_cast(unsigned short, __float2bfloat16(f));
}

// future-row remap: contiguous fut-index f -> physical row (chunks of 512)
__device__ __forceinline__ int futmap(int f) {
    return (f >> 9)*NN + SP + (f & 511);
}

// ---------------------------------------------------------------------------
// Weight prep: Wt[N][K] bf16  <-  W[K][N] fp32
// ---------------------------------------------------------------------------
__device__ __forceinline__ void wtrans_tile(
    const float* __restrict__ s, bf16* __restrict__ d, int K, int N,
    int k0, int n0)
{
    __shared__ float tile[64][65];
    int t = threadIdx.x, c = t & 63, r4 = t >> 6;
    #pragma unroll
    for (int rr = 0; rr < 64; rr += 4)
        tile[rr+r4][c] = s[(size_t)(k0+rr+r4)*N + n0 + c];
    __syncthreads();
    #pragma unroll
    for (int rr = 0; rr < 64; rr += 4) {
        int n = rr + r4;
        d[(size_t)(n0+n)*K + k0 + c] = __float2bfloat16(tile[c][n]);
    }
}

__global__ __launch_bounds__(256) void wtrans_kernel(
    const float* __restrict__ src, bf16* __restrict__ dst, int K, int N)
{
    wtrans_tile(src + (size_t)blockIdx.z*K*N, dst + (size_t)blockIdx.z*K*N,
                K, N, blockIdx.x*64, blockIdx.y*64);
}

__global__ __launch_bounds__(256) void wtrans4_kernel(
    const float* __restrict__ Wq, const float* __restrict__ Wk,
    const float* __restrict__ Wv, const float* __restrict__ Wo,
    bf16* __restrict__ Wqt, bf16* __restrict__ Wkt,
    bf16* __restrict__ Wvt, bf16* __restrict__ Wot)
{
    int z = blockIdx.z, which = z >> 3, l = z & 7;
    const float* s = (which == 0 ? Wq : which == 1 ? Wk : which == 2 ? Wv : Wo)
                     + (size_t)l*DD*DD;
    bf16* d = (which == 0 ? Wqt : which == 1 ? Wkt : which == 2 ? Wvt : Wot)
              + (size_t)l*DD*DD;
    wtrans_tile(s, d, DD, DD, blockIdx.x*64, blockIdx.y*64);
}

// ---------------------------------------------------------------------------
// bf16 MFMA GEMM core.  BM in {32,64,128}, BN=128, BK=64, 256 threads.
// fut: row-remap m0 through futmap (future-token-only last layer).
// ---------------------------------------------------------------------------
template<int BM, bool BOUT>
__device__ __forceinline__ void gemm_core(
    const bf16* __restrict__ A, const bf16* __restrict__ Wt,
    const float* __restrict__ bias, float* __restrict__ Cf,
    bf16* __restrict__ Cb, int N, int K, int epi, int kc0, int kc1, int fut)
{
    constexpr int MI = BM/32;             // M-frags per wave (>=1)
    __shared__ bf16 As[BM*64];
    __shared__ bf16 Bs[128*64];
    int tid = threadIdx.x, lane = tid & 63, wid = tid >> 6;
    int m0 = blockIdx.x*BM, n0 = blockIdx.y*128;
    if (fut) m0 = futmap(m0);
    int wm = (wid & 1)*(BM/2), wn = (wid >> 1)*64;

    f32x4 acc[MI][4] = {};

    int rA = wid*(BM/4) + (lane >> 3);
    int rB = wid*32 + (lane >> 3);
    int c_st = (lane & 7)*8;
    const bf16* Ag = A  + (size_t)(m0 + rA)*K + c_st;
    const bf16* Bg = Wt + (size_t)(n0 + rB)*K + c_st;
    bf16* Asw = As + (wid*(BM/4))*64;     // wave-uniform LDS slab base
    bf16* Bsw = Bs + (wid*32)*64;

    int a_off = (wm + (lane & 15))*64 + (lane >> 4)*8;
    int b_off = (wn + (lane & 15))*64 + (lane >> 4)*8;

    for (int kc = kc0; kc < kc1; kc += 64) {
        #pragma unroll
        for (int i = 0; i < MI; i++)
            gld_lds16(Ag + (size_t)(i*8)*K + kc, Asw + (i*8)*64);
        #pragma unroll
        for (int i = 0; i < 4; i++)
            gld_lds16(Bg + (size_t)(i*8)*K + kc, Bsw + (i*8)*64);
        __syncthreads();
        #pragma unroll
        for (int ks = 0; ks < 2; ks++) {
            bf16x8 af[MI], bfr[4];
            #pragma unroll
            for (int i = 0; i < MI; i++)
                af[i] = *(const bf16x8*)(As + a_off + i*16*64 + ks*32);
            #pragma unroll
            for (int j = 0; j < 4; j++)
                bfr[j] = *(const bf16x8*)(Bs + b_off + j*16*64 + ks*32);
            #pragma unroll
            for (int i = 0; i < MI; i++)
                #pragma unroll
                for (int j = 0; j < 4; j++)
                    acc[i][j] = __builtin_amdgcn_mfma_f32_16x16x32_bf16(
                        af[i], bfr[j], acc[i][j], 0, 0, 0);
        }
        __syncthreads();
    }

    if constexpr (BOUT) {
        // bf16 output, coalesced via LDS transpose (reuses Bs; BM<=64)
        bf16* Ct = Bs;   // BM x 128 bf16, bank-swizzled
        #pragma unroll
        for (int j = 0; j < 4; j++) {
            int col = wn + j*16 + (lane & 15);
            float bv = bias[n0 + col];
            #pragma unroll
            for (int i = 0; i < MI; i++) {
                #pragma unroll
                for (int r = 0; r < 4; r++) {
                    int row = wm + i*16 + (lane >> 4)*4 + r;
                    float v = acc[i][j][r] + bv;
                    if (epi == 1) v = fmaxf(v, 0.f);
                    else if (epi == 2) v = (v > 0.f) ? v + 1.f : expf(v);
                    Ct[row*128 + (col ^ (((row >> 2) & 3) << 4))] = __float2bfloat16(v);
                }
            }
        }
        __syncthreads();
        constexpr int NU = BM/16;        // vec8 stores per thread
        #pragma unroll
        for (int u = 0; u < NU; u++) {
            int e = (u*256 + tid)*8;
            int row = e >> 7, c0 = e & 127;
            bf16x8 val = *(const bf16x8*)(Ct + row*128 + (c0 ^ (((row >> 2) & 3) << 4)));
            *(bf16x8*)(Cb + (size_t)(m0 + row)*N + n0 + c0) = val;
        }
    } else {
        int col_base = n0 + wn + (lane & 15);
        int row_base = m0 + wm + (lane >> 4)*4;
        #pragma unroll
        for (int j = 0; j < 4; j++) {
            int col = col_base + j*16;
            float bv = bias[col];
            #pragma unroll
            for (int i = 0; i < MI; i++) {
                #pragma unroll
                for (int r = 0; r < 4; r++) {
                    int row = row_base + i*16 + r;
                    float v = acc[i][j][r] + bv;
                    if (epi == 1) v = fmaxf(v, 0.f);
                    else if (epi == 2) v = (v > 0.f) ? v + 1.f : expf(v);
                    if (Cb) Cb[(size_t)row*N + col] = __float2bfloat16(v);
                    else    Cf[(size_t)row*N + col] = v;
                }
            }
        }
    }
}

template<int BM, bool BOUT>
__global__ __launch_bounds__(256) void mfma_gemm_kernel(
    const bf16* __restrict__ A, const bf16* __restrict__ Wt,
    const float* __restrict__ bias, float* __restrict__ Cf,
    bf16* __restrict__ Cb, int N, int K, int epi, int fut)
{
    gemm_core<BM, BOUT>(A, Wt, bias, Cf, Cb, N, K, epi, 0, K, fut);
}

// QKV: fp32 outputs, BM=32; elu+1 for q,k
template<int BM>
__global__ __launch_bounds__(256) void mfma_qkv_kernel(
    const bf16* __restrict__ Xb,
    const bf16* __restrict__ Wqt, const bf16* __restrict__ Wkt, const bf16* __restrict__ Wvt,
    const float* __restrict__ bq, const float* __restrict__ bk, const float* __restrict__ bv,
    float* __restrict__ Q, float* __restrict__ K, float* __restrict__ V, int layer)
{
    int z = blockIdx.z;
    const bf16* Wt = (z == 0) ? Wqt : (z == 1) ? Wkt : Wvt;
    const float* b = (z == 0) ? bq : (z == 1) ? bk : bv;
    float* C = (z == 0) ? Q : (z == 1) ? K : V;
    gemm_core<BM, false>(Xb, Wt + (size_t)layer*DD*DD, b + (size_t)layer*DD,
                         C, nullptr, DD, DD, (z == 2) ? 0 : 2, 0, DD, 0);
}

// ---------------------------------------------------------------------------
// W2 K-slice GEMM, BN=256 (full width): slice z of K=DFF/4, fp32 partials.
// ---------------------------------------------------------------------------
__global__ __launch_bounds__(256) void w2_slice_kernel(
    const bf16* __restrict__ A, const bf16* __restrict__ Wt,
    float* __restrict__ G4, int fut)
{
    __shared__ bf16 As[32*64];
    __shared__ bf16 Bs[256*64];
    int tid = threadIdx.x, lane = tid & 63, wid = tid >> 6;
    int m0 = blockIdx.x*32;
    if (fut) m0 = futmap(m0);
    int z = blockIdx.y;
    int kc0 = z*(DFF/4), kc1 = kc0 + DFF/4;
    int wn = wid*64;

    f32x4 acc[2][4] = {};

    int rA = wid*8 + (lane >> 3);
    int c_st = (lane & 7)*8;
    const bf16* Ag = A + (size_t)(m0 + rA)*DFF + c_st;
    const bf16* Bg = Wt + (size_t)(wn + (lane >> 3))*DFF + c_st;
    bf16* Asw = As + (wid*8)*64;
    bf16* Bsw = Bs + wn*64;

    int a_off = (lane & 15)*64 + (lane >> 4)*8;
    int b_off = (wn + (lane & 15))*64 + (lane >> 4)*8;

    for (int kc = kc0; kc < kc1; kc += 64) {
        gld_lds16(Ag + kc, Asw);
        #pragma unroll
        for (int i = 0; i < 8; i++)
            gld_lds16(Bg + (size_t)(i*8)*DFF + kc, Bsw + (i*8)*64);
        __syncthreads();
        #pragma unroll
        for (int ks = 0; ks < 2; ks++) {
            bf16x8 af[2], bfr[4];
            af[0] = *(const bf16x8*)(As + a_off + ks*32);
            af[1] = *(const bf16x8*)(As + a_off + 16*64 + ks*32);
            #pragma unroll
            for (int j = 0; j < 4; j++)
                bfr[j] = *(const bf16x8*)(Bs + b_off + j*16*64 + ks*32);
            #pragma unroll
            for (int i = 0; i < 2; i++)
                #pragma unroll
                for (int j = 0; j < 4; j++)
                    acc[i][j] = __builtin_amdgcn_mfma_f32_16x16x32_bf16(
                        af[i], bfr[j], acc[i][j], 0, 0, 0);
        }
        __syncthreads();
    }

    float* Gz = G4 + (size_t)z*TOK*DD;
    #pragma unroll
    for (int j = 0; j < 4; j++) {
        int c = wn + j*16 + (lane & 15);
        #pragma unroll
        for (int i = 0; i < 2; i++) {
            int row = m0 + i*16 + (lane >> 4)*4;
            #pragma unroll
            for (int r = 0; r < 4; r++)
                Gz[(size_t)(row + r)*DD + c] = acc[i][j][r];
        }
    }
}

// ---------------------------------------------------------------------------
// Fused Wo GEMM + residual + LayerNorm1:  X = LN(X + Ab@Wo + bo)
// ---------------------------------------------------------------------------
__global__ __launch_bounds__(256) void wo_ln_kernel(
    const bf16* __restrict__ A, const bf16* __restrict__ Wt,
    const float* __restrict__ bias,
    const float* __restrict__ lnw, const float* __restrict__ lnb,
    float* __restrict__ X, bf16* __restrict__ Xb, int fut)
{
    __shared__ bf16 As[32*64];
    __shared__ bf16 Bs[256*64];
    __shared__ float red[2][4][32];
    int tid = threadIdx.x, lane = tid & 63, wid = tid >> 6;
    int m0 = blockIdx.x*32;
    if (fut) m0 = futmap(m0);
    int wn = wid*64;

    f32x4 acc[2][4] = {};

    int rA = wid*8 + (lane >> 3);
    int c_st = (lane & 7)*8;
    const bf16* Ag = A + (size_t)(m0 + rA)*DD + c_st;
    const bf16* Bg = Wt + (size_t)(wn + (lane >> 3))*DD + c_st;
    bf16* Asw = As + (wid*8)*64;
    bf16* Bsw = Bs + wn*64;

    int a_off = (lane & 15)*64 + (lane >> 4)*8;
    int b_off = (wn + (lane & 15))*64 + (lane >> 4)*8;

    for (int kc = 0; kc < DD; kc += 64) {
        gld_lds16(Ag + kc, Asw);
        #pragma unroll
        for (int i = 0; i < 8; i++)
            gld_lds16(Bg + (size_t)(i*8)*DD + kc, Bsw + (i*8)*64);
        __syncthreads();
        #pragma unroll
        for (int ks = 0; ks < 2; ks++) {
            bf16x8 af[2], bfr[4];
            af[0] = *(const bf16x8*)(As + a_off + ks*32);
            af[1] = *(const bf16x8*)(As + a_off + 16*64 + ks*32);
            #pragma unroll
            for (int j = 0; j < 4; j++)
                bfr[j] = *(const bf16x8*)(Bs + b_off + j*16*64 + ks*32);
            #pragma unroll
            for (int i = 0; i < 2; i++)
                #pragma unroll
                for (int j = 0; j < 4; j++)
                    acc[i][j] = __builtin_amdgcn_mfma_f32_16x16x32_bf16(
                        af[i], bfr[j], acc[i][j], 0, 0, 0);
        }
        __syncthreads();
    }

    // bias + residual
    #pragma unroll
    for (int j = 0; j < 4; j++) {
        int c = wn + j*16 + (lane & 15);
        float bv = bias[c];
        #pragma unroll
        for (int i = 0; i < 2; i++) {
            int row = m0 + i*16 + (lane >> 4)*4;
            #pragma unroll
            for (int r = 0; r < 4; r++)
                acc[i][j][r] += bv + X[(size_t)(row + r)*DD + c];
        }
    }
    // per-row sums
    #pragma unroll
    for (int i = 0; i < 2; i++) {
        #pragma unroll
        for (int r = 0; r < 4; r++) {
            float s  = (acc[i][0][r] + acc[i][1][r]) + (acc[i][2][r] + acc[i][3][r]);
            float s2 = (acc[i][0][r]*acc[i][0][r] + acc[i][1][r]*acc[i][1][r])
                     + (acc[i][2][r]*acc[i][2][r] + acc[i][3][r]*acc[i][3][r]);
            #pragma unroll
            for (int off = 1; off < 16; off <<= 1) {
                s  += __shfl_xor(s,  off, 64);
                s2 += __shfl_xor(s2, off, 64);
            }
            if ((lane & 15) == 0) {
                int rloc = i*16 + (lane >> 4)*4 + r;
                red[0][wid][rloc] = s;
                red[1][wid][rloc] = s2;
            }
        }
    }
    __syncthreads();
    #pragma unroll
    for (int i = 0; i < 2; i++) {
        #pragma unroll
        for (int r = 0; r < 4; r++) {
            int rloc = i*16 + (lane >> 4)*4 + r;
            float S  = (red[0][0][rloc] + red[0][1][rloc]) + (red[0][2][rloc] + red[0][3][rloc]);
            float S2 = (red[1][0][rloc] + red[1][1][rloc]) + (red[1][2][rloc] + red[1][3][rloc]);
            float mean = S * (1.f/256.f);
            float var  = S2 * (1.f/256.f) - mean*mean;
            float rs = rsqrtf(var + 1e-5f);
            #pragma unroll
            for (int j = 0; j < 4; j++) {
                int c = wn + j*16 + (lane & 15);
                float o = (acc[i][j][r] - mean) * rs * lnw[c] + lnb[c];
                size_t idx = (size_t)(m0 + rloc)*DD + c;
                X[idx] = o;
                Xb[idx] = __float2bfloat16(o);
            }
        }
    }
}

// ---------------------------------------------------------------------------
// Encoder
// ---------------------------------------------------------------------------
__global__ __launch_bounds__(256) void encode_kernel(
    const float* __restrict__ px, const float* __restrict__ py,
    const float* __restrict__ fx, const float* __restrict__ encW,
    const float* __restrict__ encb, float* __restrict__ X, bf16* __restrict__ Xb)
{
    int tok = blockIdx.x;
    int t = threadIdx.x;
    int b = tok / NN, n = tok % NN;
    __shared__ float in[24];
    if (t < 16) {
        in[t] = (n < SP) ? px[((size_t)b*SP + n)*16 + t]
                         : fx[((size_t)b*SF + (n - SP))*16 + t];
    } else if (t < 24) {
        int j = t - 16;
        in[t] = (n < SP) ? py[((size_t)b*SP + n)*8 + j]
                         : py[((size_t)b*SP + (SP-1))*8 + j];
    }
    __syncthreads();
    float acc = encb[t];
    #pragma unroll
    for (int j = 0; j < 24; j++) acc = fmaf(in[j], encW[j*DD + t], acc);
    X[(size_t)tok*DD + t] = acc;
    Xb[(size_t)tok*DD + t] = __float2bfloat16(acc);
}

// ---------------------------------------------------------------------------
// Attention pass A (fp32 K/V): per (b,h,seg) segment sums
// ---------------------------------------------------------------------------
__global__ __launch_bounds__(256) void attnA_kernel(
    const float* __restrict__ K, const float* __restrict__ V,
    float* __restrict__ SegS, float* __restrict__ SegZ)
{
    int bid = blockIdx.x;
    int seg = bid % NSEG; int bh = bid / NSEG;
    int h = bh & 7, b = bh >> 3;
    int t = threadIdx.x;
    int d = t & 31, mg = t >> 5, m0 = mg*4;
    int tok0 = b*NN + seg*SEGLEN;
    const float* Kp = K + (size_t)tok0*DD + h*DH;
    const float* Vp = V + (size_t)tok0*DD + h*DH;
    float a0=0,a1=0,a2=0,a3=0, ks=0;
    #pragma unroll 4
    for (int i = 0; i < SEGLEN; i++) {
        float kd = Kp[(size_t)i*DD + d];
        float4 vv = *(const float4*)(Vp + (size_t)i*DD + m0);
        a0 = fmaf(kd, vv.x, a0); a1 = fmaf(kd, vv.y, a1);
        a2 = fmaf(kd, vv.z, a2); a3 = fmaf(kd, vv.w, a3);
        ks += kd;
    }
    float4 o = {a0, a1, a2, a3};
    *(float4*)(SegS + ((size_t)bid*32 + d)*32 + m0) = o;
    if (mg == 0) SegZ[(size_t)bid*32 + d] = ks;
}

// ---------------------------------------------------------------------------
// Attention pass A2: in-place exclusive prefix over segments, per (b,h).
// ---------------------------------------------------------------------------
__global__ __launch_bounds__(256) void attnA2_kernel(
    float* __restrict__ SegS, float* __restrict__ SegZ)
{
    int bh = blockIdx.x, y = blockIdx.y, t = threadIdx.x;
    int e = y*256 + t;
    float* p = SegS + (size_t)bh*NSEG*1024 + e;
    float v[NSEG];
    #pragma unroll
    for (int s = 0; s < NSEG; s++) v[s] = p[(size_t)s*1024];
    float run = 0.f;
    #pragma unroll
    for (int s = 0; s < NSEG; s++) {
        p[(size_t)s*1024] = run;
        run += v[s];
    }
    if (y == 0 && t < 32) {
        float* pz = SegZ + (size_t)bh*NSEG*32 + t;
        float vz[NSEG];
        #pragma unroll
        for (int s = 0; s < NSEG; s++) vz[s] = pz[(size_t)s*32];
        float runz = 0.f;
        #pragma unroll
        for (int s = 0; s < NSEG; s++) {
            pz[(size_t)s*32] = runz;
            runz += vz[s];
        }
    }
}

// ---------------------------------------------------------------------------
// Attention pass B: TWO waves per (b,h,seg), 4 waves/block (2 segments).
// seg0/nsegl: restrict processed segments (last layer: 32..47 only).
// ---------------------------------------------------------------------------
__global__ __launch_bounds__(256) void attnB_kernel(
    const float* __restrict__ Q, const float* __restrict__ K, const float* __restrict__ V,
    const float* __restrict__ SegS, const float* __restrict__ SegZ,
    bf16* __restrict__ A, int seg0, int nsegl)
{
    int tid = threadIdx.x;
    int sidx = tid >> 7;                 // segment slot in block (0..1)
    int half = (tid >> 6) & 1;           // m-half
    int lane = tid & 63;
    int lbid = blockIdx.x*2 + sidx;      // local id
    int seg = seg0 + lbid % nsegl;
    int bh = lbid / nsegl;
    int gbid = bh*NSEG + seg;            // global (b,h,seg) id for SegS/SegZ
    int h = bh & 7, b = bh >> 3;
    int m = half*16 + (lane & 15);       // 0..31
    int d0 = (lane >> 4)*8;              // d-group base
    int tok0 = b*NN + seg*SEGLEN;

    __shared__ float qs[2][SEGLEN][32], ksm[2][SEGLEN][32], vs[2][SEGLEN][32];
    const float* Qp = Q + (size_t)tok0*DD + h*DH;
    const float* Kp = K + (size_t)tok0*DD + h*DH;
    const float* Vp = V + (size_t)tok0*DD + h*DH;
    int lt = tid & 127;                  // 128 threads per segment
    #pragma unroll
    for (int f = lt; f < SEGLEN*8; f += 128) {
        int r = f >> 3, c = (f & 7)*4;
        *(float4*)&qs[sidx][r][c]  = *(const float4*)(Qp + (size_t)r*DD + c);
        *(float4*)&ksm[sidx][r][c] = *(const float4*)(Kp + (size_t)r*DD + c);
        *(float4*)&vs[sidx][r][c]  = *(const float4*)(Vp + (size_t)r*DD + c);
    }
    __syncthreads();

    float kv[8], kss[8];
    const float* Pp = SegS + (size_t)gbid*1024;
    const float* Zp = SegZ + (size_t)gbid*32;
    #pragma unroll
    for (int j = 0; j < 8; j++) {
        kv[j]  = Pp[(d0 + j)*32 + m];
        kss[j] = Zp[d0 + j];
    }

    bf16* Ap = A + (size_t)tok0*DD + h*DH;
    for (int i = 0; i < SEGLEN; i++) {
        float qv[8], kk[8];
        #pragma unroll
        for (int c = 0; c < 2; c++) {
            float4 t4 = *(const float4*)&qs[sidx][i][d0 + 4*c];
            qv[4*c] = t4.x; qv[4*c+1] = t4.y; qv[4*c+2] = t4.z; qv[4*c+3] = t4.w;
            float4 k4 = *(const float4*)&ksm[sidx][i][d0 + 4*c];
            kk[4*c] = k4.x; kk[4*c+1] = k4.y; kk[4*c+2] = k4.z; kk[4*c+3] = k4.w;
        }
        float vm = vs[sidx][i][m];
        #pragma unroll
        for (int j = 0; j < 8; j++) {
            kv[j] = fmaf(kk[j], vm, kv[j]);
            kss[j] += kk[j];
        }
        float p0=0,p1=0,z0=0,z1=0;
        #pragma unroll
        for (int j = 0; j < 4; j++) {
            p0 = fmaf(qv[j],   kv[j],   p0);
            p1 = fmaf(qv[4+j], kv[4+j], p1);
            z0 = fmaf(qv[j],   kss[j],  z0);
            z1 = fmaf(qv[4+j], kss[4+j],z1);
        }
        float nump = p0 + p1;
        float zp   = z0 + z1;
        nump += __shfl_xor(nump, 16, 64);
        nump += __shfl_xor(nump, 32, 64);
        zp   += __shfl_xor(zp,   16, 64);
        zp   += __shfl_xor(zp,   32, 64);
        if ((lane >> 4) == 0)    // lanes 0..15 hold the full sums
            Ap[(size_t)i*DD + m] = __float2bfloat16(nump / (zp + 1e-6f));
    }
}

// ---------------------------------------------------------------------------
// Residual + 4-slice sum + LayerNorm -> X fp32 and Xb bf16.
// ---------------------------------------------------------------------------
__global__ __launch_bounds__(256) void resid_ln4_kernel(
    const float* __restrict__ Xin, const float* __restrict__ G4,
    const float* __restrict__ gb,
    const float* __restrict__ w, const float* __restrict__ b,
    float* __restrict__ Xout, bf16* __restrict__ Xbout, int fut)
{
    const size_t SZ = (size_t)TOK*DD;
    int tok = blockIdx.x, t = threadIdx.x;
    if (fut) tok = futmap(tok);
    size_t idx = (size_t)tok*DD + t;
    float v = Xin[idx] + gb[t]
            + ((G4[idx] + G4[SZ + idx]) + (G4[2*SZ + idx] + G4[3*SZ + idx]));
    float s = v, s2 = v*v;
    #pragma unroll
    for (int off = 32; off >= 1; off >>= 1) {
        s  += __shfl_xor(s,  off, 64);
        s2 += __shfl_xor(s2, off, 64);
    }
    __shared__ float ps[4], ps2[4];
    int wid = t >> 6;
    if ((t & 63) == 0) { ps[wid] = s; ps2[wid] = s2; }
    __syncthreads();
    float S  = ps[0] + ps[1] + ps[2] + ps[3];
    float S2 = ps2[0] + ps2[1] + ps2[2] + ps2[3];
    float mean = S * (1.f/256.f);
    float var  = S2 * (1.f/256.f) - mean*mean;
    float o = (v - mean) * rsqrtf(var + 1e-5f) * w[t] + b[t];
    Xout[idx] = o;
    Xbout[idx] = __float2bfloat16(o);
}

// ---------------------------------------------------------------------------
// Head
// ---------------------------------------------------------------------------
__global__ __launch_bounds__(256) void head_kernel(
    const float* __restrict__ X,
    const float* __restrict__ meanW, const float* __restrict__ meanB,
    const float* __restrict__ stdW,  const float* __restrict__ stdB,
    float* __restrict__ out)
{
    int wv = threadIdx.x >> 6;
    int lane = threadIdx.x & 63;
    int idx = blockIdx.x*4 + wv;
    int b = idx / SF, i = idx % SF;
    const float* row = X + ((size_t)(b*NN + SP + i))*DD;
    __shared__ float xs[4][DD];
    *(float4*)&xs[wv][lane*4] = *(const float4*)(row + lane*4);
    __syncthreads();

    int j = lane & 7;
    int which = (lane >> 3) & 1;
    int seg = lane >> 4;
    const float* W = which ? stdW : meanW;
    float p = 0.f;
    #pragma unroll 16
    for (int d = seg*64; d < seg*64 + 64; d++) p = fmaf(xs[wv][d], W[d*8 + j], p);
    p += __shfl_xor(p, 16, 64);
    p += __shfl_xor(p, 32, 64);
    if (lane < 16) {
        if (which == 0) {
            out[((size_t)b*SF + i)*8 + j] = p + meanB[j];
        } else {
            float s = p + stdB[j];
            float sp = fmaxf(s, 0.f) + log1pf(expf(-fabsf(s)));
            out[(size_t)BB*SF*8 + ((size_t)b*SF + i)*8 + j] = 0.01f + 0.99f*sp;
        }
    }
}

// ---------------------------------------------------------------------------
extern "C" void kernel_launch(void* const* d_in, const int* in_sizes, int n_in,
                              void* d_out, int out_size, void* d_ws, size_t ws_size,
                              hipStream_t stream)
{
    (void)in_sizes; (void)n_in; (void)out_size; (void)ws_size;
    const float* past_x   = (const float*)d_in[0];
    const float* past_y   = (const float*)d_in[1];
    const float* future_x = (const float*)d_in[2];
    const float* enc_W    = (const float*)d_in[3];
    const float* enc_b    = (const float*)d_in[4];
    const float* Wq       = (const float*)d_in[5];
    const float* bq       = (const float*)d_in[6];
    const float* Wk       = (const float*)d_in[7];
    const float* bk       = (const float*)d_in[8];
    const float* Wv       = (const float*)d_in[9];
    const float* bv       = (const float*)d_in[10];
    const float* Wo       = (const float*)d_in[11];
    const float* bo       = (const float*)d_in[12];
    const float* ln1_w    = (const float*)d_in[13];
    const float* ln1_b    = (const float*)d_in[14];
    const float* W1       = (const float*)d_in[15];
    const float* b1       = (const float*)d_in[16];
    const float* W2       = (const float*)d_in[17];
    const float* b2       = (const float*)d_in[18];
    const float* ln2_w    = (const float*)d_in[19];
    const float* ln2_b    = (const float*)d_in[20];
    const float* mean_W   = (const float*)d_in[21];
    const float* mean_b   = (const float*)d_in[22];
    const float* std_W    = (const float*)d_in[23];
    const float* std_b    = (const float*)d_in[24];
    float* out = (float*)d_out;

    char* base = (char*)d_ws;
    size_t off = 0;
    float* X  = (float*)(base + off); off += (size_t)TOK*DD*4;
    bf16* Xb  = (bf16*)(base + off);  off += (size_t)TOK*DD*2;
    bf16* Hb  = (bf16*)(base + off);  off += (size_t)TOK*DFF*2;   // aliased with Q/K/V
    float* Qb = (float*)Hb;
    float* Kb = Qb + (size_t)TOK*DD;
    float* Vb = Kb + (size_t)TOK*DD;
    bf16* Ab  = (bf16*)(base + off);  off += (size_t)TOK*DD*2;
    float* G4 = (float*)(base + off); off += (size_t)4*TOK*DD*4;
    float* SegS = (float*)(base + off); off += (size_t)BB*HH*NSEG*1024*4;
    float* SegZ = (float*)(base + off); off += (size_t)BB*HH*NSEG*32*4;
    bf16* Wqt = (bf16*)(base + off); off += (size_t)LL*DD*DD*2;
    bf16* Wkt = (bf16*)(base + off); off += (size_t)LL*DD*DD*2;
    bf16* Wvt = (bf16*)(base + off); off += (size_t)LL*DD*DD*2;
    bf16* Wot = (bf16*)(base + off); off += (size_t)LL*DD*DD*2;
    bf16* W1t = (bf16*)(base + off); off += (size_t)LL*DD*DFF*2;
    bf16* W2t = (bf16*)(base + off); off += (size_t)LL*DFF*DD*2;

    // Weight prep (bf16 + transpose to [N][K])
    wtrans4_kernel<<<dim3(4, 4, 4*LL), 256, 0, stream>>>(
        Wq, Wk, Wv, Wo, Wqt, Wkt, Wvt, Wot);
    wtrans_kernel<<<dim3(4, 32, LL), 256, 0, stream>>>(W1, W1t, DD, DFF);
    wtrans_kernel<<<dim3(32, 4, LL), 256, 0, stream>>>(W2, W2t, DFF, DD);

    encode_kernel<<<TOK, 256, 0, stream>>>(past_x, past_y, future_x, enc_W, enc_b, X, Xb);

    for (int l = 0; l < LL; l++) {
        int last = (l == LL - 1);
        mfma_qkv_kernel<32><<<dim3(TOK/32, 2, 3), 256, 0, stream>>>(
            Xb, Wqt, Wkt, Wvt, bq, bk, bv, Qb, Kb, Vb, l);
        attnA_kernel<<<BB*HH*NSEG, 256, 0, stream>>>(Kb, Vb, SegS, SegZ);
        attnA2_kernel<<<dim3(BB*HH, 4), 256, 0, stream>>>(SegS, SegZ);
        if (!last) {
            attnB_kernel<<<BB*HH*NSEG/2, 256, 0, stream>>>(
                Qb, Kb, Vb, SegS, SegZ, Ab, 0, NSEG);
            wo_ln_kernel<<<TOK/32, 256, 0, stream>>>(
                Ab, Wot + (size_t)l*DD*DD, bo + (size_t)l*DD,
                ln1_w + l*DD, ln1_b + l*DD, X, Xb, 0);
            mfma_gemm_kernel<32, true><<<dim3(TOK/32, DFF/128), 256, 0, stream>>>(
                Xb, W1t + (size_t)l*DD*DFF, b1 + (size_t)l*DFF, nullptr, Hb, DFF, DD, 1, 0);
            w2_slice_kernel<<<dim3(TOK/32, 4), 256, 0, stream>>>(
                Hb, W2t + (size_t)l*DFF*DD, G4, 0);
            resid_ln4_kernel<<<TOK, 256, 0, stream>>>(
                X, G4, b2 + (size_t)l*DD, ln2_w + l*DD, ln2_b + l*DD, X, Xb, 0);
        } else {
            // last layer: only future tokens feed the head
            attnB_kernel<<<BB*HH*16/2, 256, 0, stream>>>(
                Qb, Kb, Vb, SegS, SegZ, Ab, 32, 16);
            wo_ln_kernel<<<FTOK/32, 256, 0, stream>>>(
                Ab, Wot + (size_t)l*DD*DD, bo + (size_t)l*DD,
                ln1_w + l*DD, ln1_b + l*DD, X, Xb, 1);
            mfma_gemm_kernel<32, true><<<dim3(FTOK/32, DFF/128), 256, 0, stream>>>(
                Xb, W1t + (size_t)l*DD*DFF, b1 + (size_t)l*DFF, nullptr, Hb, DFF, DD, 1, 1);
            w2_slice_kernel<<<dim3(FTOK/32, 4), 256, 0, stream>>>(
                Hb, W2t + (size_t)l*DFF*DD, G4, 1);
            resid_ln4_kernel<<<FTOK, 256, 0, stream>>>(
                X, G4, b2 + (size_t)l*DD, ln2_w + l*DD, ln2_b + l*DD, X, Xb, 1);
        }
    }

    head_kernel<<<(BB*SF)/4, 256, 0, stream>>>(X, mean_W, mean_b, std_W, std_b, out);
}